// Round 1
// baseline (37029.419 us; speedup 1.0000x reference)
//
#include <hip/hip_runtime.h>
#include <math.h>

// Problem constants
constexpr int B_ = 4, T_ = 577, N_ = 576, D_ = 1024, G_ = 48, H_ = 16;
constexpr int NEED_ = 192, L_ = 191;
constexpr int TRIU_CNT = N_ * (N_ - 1) / 2; // 165600

// ---------------- workspace layout (bytes) ----------------
constexpr size_t OF_MSIG = 0;                                    // f32 B*N*D (aliased by invit solver scratch later)
constexpr size_t OF_SIM  = OF_MSIG + (size_t)B_*N_*D_*4;
constexpr size_t OF_A    = OF_SIM  + (size_t)B_*N_*N_*4;         // f64 Gram (also holds Householder vectors in rows)
constexpr size_t OF_MS   = OF_A    + (size_t)B_*N_*N_*8;         // f64 sigmoid row sums
constexpr size_t OF_INVN = OF_MS   + (size_t)B_*N_*8;            // f64 1/norm of raw hs rows
constexpr size_t OF_CLS  = OF_INVN + (size_t)B_*N_*8;            // f32 cls attention sums
constexpr size_t OF_DT   = OF_CLS  + (size_t)B_*N_*4;            // f64 tridiag diagonal
constexpr size_t OF_ET   = OF_DT   + (size_t)B_*N_*8;            // f64 tridiag off-diagonal
constexpr size_t OF_TAU  = OF_ET   + (size_t)B_*N_*8;            // f64 Householder taus
constexpr size_t OF_EVAL = OF_TAU  + (size_t)B_*N_*8;            // f64 top-48 eigenvalues (descending)
constexpr size_t OF_Z    = OF_EVAL + (size_t)B_*G_*8;            // f64 eigenvectors [b][q][i]
constexpr size_t OF_NS   = OF_Z    + (size_t)B_*G_*N_*8;         // f32 NMS working scores [n*G+g]
constexpr size_t OF_RS   = OF_NS   + (size_t)B_*N_*G_*4;         // f32 ret scores
constexpr size_t OF_PART = OF_RS   + (size_t)B_*N_*G_*4;         // f64 simmean partials B*36
constexpr size_t OF_THR  = OF_PART + (size_t)B_*36*8;            // f32 thresholds (padded)
constexpr size_t OF_BEL  = OF_THR  + 64;                         // int belong
constexpr size_t WS_NEEDED = OF_BEL + (size_t)B_*N_*4;

__device__ __forceinline__ double blockReduceD(double x, double* red) {
  int lane = threadIdx.x & 63, wv = threadIdx.x >> 6;
  int nw = (blockDim.x + 63) >> 6;
  for (int o = 32; o > 0; o >>= 1) x += __shfl_down(x, o);
  __syncthreads();                // protect red from previous use
  if (lane == 0) red[wv] = x;
  __syncthreads();
  double t = red[0];
  for (int i = 1; i < nw; i++) t += red[i];
  return t;                       // same deterministic value on all threads
}

// -------- K1: sigmoid features, row sums, inverse norms --------
__global__ void k_prep(const float* __restrict__ hs, float* __restrict__ msig,
                       double* __restrict__ ms, double* __restrict__ invn) {
  __shared__ double red[16];
  int bn = blockIdx.x; int b = bn / N_, n = bn % N_;
  const float* row = hs + ((size_t)b*T_ + (n+1)) * (size_t)D_;
  float* mrow = msig + (size_t)bn * D_;
  double ssig = 0.0, ssq = 0.0;
  for (int d = threadIdx.x; d < D_; d += blockDim.x) {
    float x = row[d];
    float sg = 1.0f / (1.0f + expf(-x));
    mrow[d] = sg;
    ssig += (double)sg;
    ssq  += (double)x * (double)x;
  }
  double tot_sig = blockReduceD(ssig, red);
  double tot_sq  = blockReduceD(ssq, red);
  if (threadIdx.x == 0) {
    ms[bn] = tot_sig;
    invn[bn] = 1.0 / fmax(sqrt(tot_sq), 1e-12);
  }
}

// -------- K2: cls attention sums (sequential over heads, matching np axis-1 reduce) --------
__global__ void k_cls(const float* __restrict__ attn, float* __restrict__ cls) {
  int idx = blockIdx.x * blockDim.x + threadIdx.x;
  if (idx >= B_ * N_) return;
  int b = idx / N_, n = idx % N_;
  float s = 0.0f;
  for (int h = 0; h < H_; h++)
    s += attn[(((size_t)b*H_ + h) * T_ + 0) * T_ + (1 + n)];
  cls[idx] = s;
}

// -------- K3: tiled X*X^T GEMM; mode0 -> Gram (f64), mode1 -> cosine sim (f32) --------
__global__ void k_gemm(const float* __restrict__ hs, const float* __restrict__ msig,
                       const double* __restrict__ ms, const double* __restrict__ invn,
                       double* __restrict__ Aout, float* __restrict__ sim, int mode) {
  __shared__ float As[32][17], Bs[32][17];
  int b = blockIdx.z;
  int bi0 = blockIdx.y * 32, bj0 = blockIdx.x * 32;
  const float* base = (mode == 0) ? (msig + (size_t)b*N_*D_)
                                  : (hs + ((size_t)b*T_ + 1) * (size_t)D_);
  int tid = threadIdx.x;
  int tx = tid & 15, ty = tid >> 4;
  double a00 = 0, a01 = 0, a10 = 0, a11 = 0;
  for (int k0 = 0; k0 < D_; k0 += 16) {
    int r = tid >> 4, c = tid & 15;
    As[r][c] = base[(size_t)(bi0 + r) * D_ + k0 + c];
    Bs[r][c] = base[(size_t)(bj0 + r) * D_ + k0 + c];
    int e = tid + 256; r = e >> 4; c = e & 15;
    As[r][c] = base[(size_t)(bi0 + r) * D_ + k0 + c];
    Bs[r][c] = base[(size_t)(bj0 + r) * D_ + k0 + c];
    __syncthreads();
#pragma unroll
    for (int kk = 0; kk < 16; kk++) {
      double x0 = As[2*ty][kk],   x1 = As[2*ty+1][kk];
      double y0 = Bs[2*tx][kk],   y1 = Bs[2*tx+1][kk];
      a00 += x0*y0; a01 += x0*y1; a10 += x1*y0; a11 += x1*y1;
    }
    __syncthreads();
  }
  int i0 = bi0 + 2*ty, j0 = bj0 + 2*tx;
  if (mode == 0) {
    const double* msb = ms + (size_t)b*N_;
    double* Ab = Aout + (size_t)b*N_*N_;
    const double inv1024 = 1.0 / 1024.0;
    Ab[(size_t)i0*N_ + j0]         = a00 - msb[i0]*msb[j0]*inv1024;
    Ab[(size_t)i0*N_ + j0+1]       = a01 - msb[i0]*msb[j0+1]*inv1024;
    Ab[(size_t)(i0+1)*N_ + j0]     = a10 - msb[i0+1]*msb[j0]*inv1024;
    Ab[(size_t)(i0+1)*N_ + j0+1]   = a11 - msb[i0+1]*msb[j0+1]*inv1024;
  } else {
    const double* iv = invn + (size_t)b*N_;
    float* sb = sim + (size_t)b*N_*N_;
    sb[(size_t)i0*N_ + j0]       = (float)(a00 * iv[i0]*iv[j0]);
    sb[(size_t)i0*N_ + j0+1]     = (float)(a01 * iv[i0]*iv[j0+1]);
    sb[(size_t)(i0+1)*N_ + j0]   = (float)(a10 * iv[i0+1]*iv[j0]);
    sb[(size_t)(i0+1)*N_ + j0+1] = (float)(a11 * iv[i0+1]*iv[j0+1]);
  }
}

// -------- K4: upper-triangle sum partials --------
__global__ void k_simsum(const float* __restrict__ sim, double* __restrict__ part) {
  __shared__ double red[4];
  int blk = blockIdx.x; int b = blk / 36, s = blk % 36;
  const float* sb = sim + (size_t)b*N_*N_;
  double p = 0.0;
  for (int i = s*16; i < s*16 + 16; i++) {
    const float* row = sb + (size_t)i*N_;
    for (int j = i + 1 + threadIdx.x; j < N_; j += blockDim.x) p += (double)row[j];
  }
  double t = blockReduceD(p, red);
  if (threadIdx.x == 0) part[blk] = t;
}

__global__ void k_thr(const double* __restrict__ part, float* __restrict__ thrF) {
  int b = threadIdx.x;
  if (b < B_) {
    double s = 0.0;
    for (int i = 0; i < 36; i++) s += part[b*36 + i];
    thrF[b] = 6.0f * (float)(s / (double)TRIU_CNT);
  }
}

// -------- K5: Householder tridiagonalization (one block per batch) --------
__global__ __launch_bounds__(1024) void k_tridiag(double* __restrict__ Aall,
    double* __restrict__ dT, double* __restrict__ eT, double* __restrict__ tauT) {
  __shared__ double v[N_], w[N_];
  __shared__ double red[16];
  __shared__ double sh_alpha, sh_tau, sh_K;
  int b = blockIdx.x;
  double* A  = Aall + (size_t)b*N_*N_;
  double* d  = dT   + (size_t)b*N_;
  double* e  = eT   + (size_t)b*N_;
  double* tau = tauT + (size_t)b*N_;
  int tid = threadIdx.x, lane = tid & 63, wv = tid >> 6;
  for (int k = 0; k < N_ - 2; k++) {
    double ps = 0.0;
    for (int i = k + 1 + tid; i < N_; i += 1024) {
      double x = A[(size_t)i*N_ + k];
      v[i] = x; ps += x * x;
    }
    double sigma = blockReduceD(ps, red);
    if (tid == 0) {
      double x0 = v[k + 1];
      d[k] = A[(size_t)k*N_ + k];
      if (sigma == 0.0) { sh_tau = 0.0; e[k] = 0.0; tau[k] = 0.0; }
      else {
        double alpha = (x0 >= 0.0) ? -sqrt(sigma) : sqrt(sigma);
        sh_alpha = alpha;
        double t = 1.0 / (sigma - alpha * x0);
        sh_tau = t; e[k] = alpha; tau[k] = t;
      }
    }
    __syncthreads();
    double tloc = sh_tau;
    if (tloc == 0.0) continue;
    if (tid == 0) v[k + 1] -= sh_alpha;
    __syncthreads();
    // store v in row k for back-transform
    for (int i = k + 1 + tid; i < N_; i += 1024) A[(size_t)k*N_ + i] = v[i];
    // p = tau * A_sub * v  (wave per row)
    for (int r = k + 1 + wv; r < N_; r += 16) {
      const double* Ar = A + (size_t)r*N_;
      double pd = 0.0;
      for (int j = k + 1 + lane; j < N_; j += 64) pd += Ar[j] * v[j];
      for (int o = 32; o > 0; o >>= 1) pd += __shfl_down(pd, o);
      if (lane == 0) w[r] = tloc * pd;
    }
    __syncthreads();
    double pk = 0.0;
    for (int i = k + 1 + tid; i < N_; i += 1024) pk += v[i] * w[i];
    double vtp = blockReduceD(pk, red);
    if (tid == 0) sh_K = 0.5 * tloc * vtp;
    __syncthreads();
    double Kc = sh_K;
    for (int i = k + 1 + tid; i < N_; i += 1024) w[i] -= Kc * v[i];
    __syncthreads();
    int ty2 = tid >> 5, tx2 = tid & 31;
    for (int i = k + 1 + ty2; i < N_; i += 32) {
      double vi = v[i], wi = w[i];
      double* Ai = A + (size_t)i*N_;
      for (int j = k + 1 + tx2; j < N_; j += 32)
        Ai[j] -= vi * w[j] + wi * v[j];
    }
    __syncthreads();
  }
  if (tid == 0) {
    d[N_-2] = A[(size_t)(N_-2)*N_ + (N_-2)];
    d[N_-1] = A[(size_t)(N_-1)*N_ + (N_-1)];
    e[N_-2] = A[(size_t)(N_-1)*N_ + (N_-2)];
    e[N_-1] = 0.0;
    tau[N_-2] = 0.0; tau[N_-1] = 0.0;
  }
}

// -------- K6: top-48 eigenvalues by Sturm bisection (lane per eigenvalue) --------
__global__ void k_eigvals(const double* __restrict__ dT, const double* __restrict__ eT,
                          double* __restrict__ eval) {
  __shared__ double sd[N_], se[N_];
  int b = blockIdx.x;
  for (int i = threadIdx.x; i < N_; i += blockDim.x) {
    sd[i] = dT[(size_t)b*N_ + i];
    se[i] = eT[(size_t)b*N_ + i];
  }
  __syncthreads();
  int j = threadIdx.x;
  if (j < G_) {
    double lo = 1e300, hi = -1e300;
    for (int i = 0; i < N_; i++) {
      double r = ((i > 0) ? fabs(se[i-1]) : 0.0) + ((i < N_-1) ? fabs(se[i]) : 0.0);
      lo = fmin(lo, sd[i] - r); hi = fmax(hi, sd[i] + r);
    }
    double span = hi - lo + 1e-30;
    lo -= span * 1e-6; hi += span * 1e-6;
    int target = N_ - 1 - j;  // ascending index of j-th largest
    const double PIV = 1e-280;
    for (int it = 0; it < 80; it++) {
      double mid = 0.5 * (lo + hi);
      int cnt = 0;
      double q = sd[0] - mid;
      if (q <= PIV) { cnt++; q = fmin(q, -PIV); }
      for (int i = 1; i < N_; i++) {
        q = (sd[i] - mid) - se[i-1]*se[i-1] / q;
        if (q <= PIV) { cnt++; q = fmin(q, -PIV); }
      }
      if (cnt > target) hi = mid; else lo = mid;
    }
    eval[(size_t)b*G_ + j] = 0.5 * (lo + hi);
  }
}

// -------- K7: inverse iteration (lane per eigenvector) + rare cluster re-orth --------
__global__ void k_eigvecs(const double* __restrict__ dT, const double* __restrict__ eT,
    const double* __restrict__ eval,
    double* __restrict__ Ud, double* __restrict__ U1, double* __restrict__ U2,
    double* __restrict__ Um, int* __restrict__ Ufl, double* __restrict__ Yv,
    double* __restrict__ Z) {
  __shared__ double sd[N_], se[N_];
  __shared__ double red0;
  __shared__ int cstart[G_];
  __shared__ double sh_ev[G_];
  int b = blockIdx.x;
  for (int i = threadIdx.x; i < N_; i += blockDim.x) {
    sd[i] = dT[(size_t)b*N_ + i]; se[i] = eT[(size_t)b*N_ + i];
  }
  if (threadIdx.x < G_) sh_ev[threadIdx.x] = eval[(size_t)b*G_ + threadIdx.x];
  __syncthreads();
  int j = threadIdx.x;
  size_t sbase = (size_t)b * N_ * G_;
  double* ud = Ud + sbase; double* u1 = U1 + sbase; double* u2 = U2 + sbase;
  double* um = Um + sbase; int* ufl = Ufl + sbase; double* yv = Yv + sbase;
  if (j < G_) {
    double lam = sh_ev[j];
    double GU = 1e-30 * (1.0 + fabs(lam));
    // factor T - lam with partial pivoting
    double ak = sd[0] - lam;
    double bk = se[0];
    for (int k = 0; k < N_ - 1; k++) {
      double sub = se[k];
      double diag1 = sd[k+1] - lam;
      double sup1 = (k < N_ - 2) ? se[k+1] : 0.0;
      double udv, u1v, u2v, umv; int flv;
      if (fabs(ak) >= fabs(sub)) {
        double piv = ak;
        if (fabs(piv) < GU) piv = (piv >= 0.0) ? GU : -GU;
        double ml = sub / piv;
        udv = piv; u1v = bk; u2v = 0.0; umv = ml; flv = 0;
        ak = diag1 - ml * bk; bk = sup1;
      } else {
        double ml = ak / sub;
        udv = sub; u1v = diag1; u2v = sup1; umv = ml; flv = 1;
        ak = bk - ml * diag1; bk = -ml * sup1;
      }
      ud[(size_t)k*G_+j] = udv; u1[(size_t)k*G_+j] = u1v; u2[(size_t)k*G_+j] = u2v;
      um[(size_t)k*G_+j] = umv; ufl[(size_t)k*G_+j] = flv;
    }
    { double piv = ak; if (fabs(piv) < GU) piv = (piv >= 0.0) ? GU : -GU;
      ud[(size_t)(N_-1)*G_+j] = piv; u1[(size_t)(N_-1)*G_+j] = 0.0; u2[(size_t)(N_-1)*G_+j] = 0.0; }
    // deterministic pseudo-random rhs
    for (int i = 0; i < N_; i++) {
      unsigned s = (unsigned)(i * 2654435761u) ^ (unsigned)((j + 1) * 40503u) ^ (unsigned)(b * 2246822519u);
      s = s * 1664525u + 1013904223u;
      s ^= s >> 16; s = s * 2246822519u;
      double rv = ((double)(s >> 8) * (1.0 / 16777216.0)) * 2.0 - 1.0;
      if (fabs(rv) < 1e-3) rv = 0.5;
      yv[(size_t)i*G_+j] = rv;
    }
    for (int it = 0; it < 3; it++) {
      if (it) {
        double mx = 0.0;
        for (int i = 0; i < N_; i++) mx = fmax(mx, fabs(yv[(size_t)i*G_+j]));
        double sc = 1.0 / fmax(mx, 1e-300);
        for (int i = 0; i < N_; i++) yv[(size_t)i*G_+j] *= sc;
      }
      // forward
      for (int k = 0; k < N_ - 1; k++) {
        double yk = yv[(size_t)k*G_+j], yk1 = yv[(size_t)(k+1)*G_+j];
        if (ufl[(size_t)k*G_+j]) { double t = yk; yk = yk1; yk1 = t; }
        yk1 -= um[(size_t)k*G_+j] * yk;
        yv[(size_t)k*G_+j] = yk; yv[(size_t)(k+1)*G_+j] = yk1;
      }
      // back
      double y1, y2 = 0.0;
      { double t = yv[(size_t)(N_-1)*G_+j] / ud[(size_t)(N_-1)*G_+j];
        yv[(size_t)(N_-1)*G_+j] = t; y1 = t; }
      for (int k = N_ - 2; k >= 0; k--) {
        double t = yv[(size_t)k*G_+j] - u1[(size_t)k*G_+j]*y1 - u2[(size_t)k*G_+j]*y2;
        t /= ud[(size_t)k*G_+j];
        yv[(size_t)k*G_+j] = t;
        y2 = y1; y1 = t;
      }
    }
    double s2 = 0.0;
    for (int i = 0; i < N_; i++) { double t = yv[(size_t)i*G_+j]; s2 += t * t; }
    double inv = 1.0 / sqrt(fmax(s2, 1e-300));
    double* Zj = Z + ((size_t)b*G_ + j) * N_;
    for (int i = 0; i < N_; i++) Zj[i] = yv[(size_t)i*G_+j] * inv;
  }
  __syncthreads();
  // cluster re-orthogonalization (rarely triggers)
  if (threadIdx.x == 0) {
    double tol = 1e-10 * (fabs(sh_ev[0]) + 1.0);
    cstart[0] = 0;
    for (int q = 1; q < G_; q++)
      cstart[q] = ((sh_ev[q-1] - sh_ev[q]) < tol) ? cstart[q-1] : q;
  }
  __syncthreads();
  for (int q = 1; q < G_; q++) {
    if (cstart[q] == q) continue;
    double* Zq = Z + ((size_t)b*G_ + q) * N_;
    for (int p = cstart[q]; p < q; p++) {
      double* Zp = Z + ((size_t)b*G_ + p) * N_;
      double dp = 0.0;
      for (int i = threadIdx.x; i < N_; i += blockDim.x) dp += Zq[i] * Zp[i];
      for (int o = 32; o > 0; o >>= 1) dp += __shfl_down(dp, o);
      if (threadIdx.x == 0) red0 = dp;
      __syncthreads();
      double dd = red0;
      for (int i = threadIdx.x; i < N_; i += blockDim.x) Zq[i] -= dd * Zp[i];
      __syncthreads();
    }
    double s2 = 0.0;
    for (int i = threadIdx.x; i < N_; i += blockDim.x) { double t = Zq[i]; s2 += t * t; }
    for (int o = 32; o > 0; o >>= 1) s2 += __shfl_down(s2, o);
    if (threadIdx.x == 0) red0 = s2;
    __syncthreads();
    double inv = 1.0 / sqrt(fmax(red0, 1e-300));
    for (int i = threadIdx.x; i < N_; i += blockDim.x) Zq[i] *= inv;
    __syncthreads();
  }
}

// -------- K8: back-transform eigenvectors through stored reflectors --------
__global__ __launch_bounds__(1024) void k_backxf(const double* __restrict__ Aall,
    const double* __restrict__ tauT, double* __restrict__ Z) {
  __shared__ double v[N_];
  __shared__ double sdot[G_];
  __shared__ double sh_t;
  int b = blockIdx.x;
  const double* A = Aall + (size_t)b*N_*N_;
  double* Zb = Z + (size_t)b*G_*N_;
  int tid = threadIdx.x, lane = tid & 63, wv = tid >> 6;
  for (int k = N_ - 3; k >= 0; k--) {
    __syncthreads();
    if (tid == 0) sh_t = tauT[(size_t)b*N_ + k];
    __syncthreads();
    double t = sh_t;
    if (t == 0.0) continue;
    for (int i = k + 1 + tid; i < N_; i += 1024) v[i] = A[(size_t)k*N_ + i];
    __syncthreads();
    for (int q = wv; q < G_; q += 16) {
      const double* Zq = Zb + (size_t)q*N_;
      double p = 0.0;
      for (int i = k + 1 + lane; i < N_; i += 64) p += v[i] * Zq[i];
      for (int o = 32; o > 0; o >>= 1) p += __shfl_down(p, o);
      if (lane == 0) sdot[q] = p;
    }
    __syncthreads();
    for (int q = wv; q < G_; q += 16) {
      double* Zq = Zb + (size_t)q*N_;
      double s = t * sdot[q];
      for (int i = k + 1 + lane; i < N_; i += 64) Zq[i] -= s * v[i];
    }
  }
}

// -------- K9: belong = argmax_q |V[n][q]| (first max) --------
__global__ void k_belong(const double* __restrict__ Z, int* __restrict__ belong) {
  int idx = blockIdx.x * blockDim.x + threadIdx.x;
  if (idx >= B_ * N_) return;
  int b = idx / N_, n = idx % N_;
  const double* Zb = Z + (size_t)b*G_*N_;
  double best = -1.0; int bi = 0;
  for (int q = 0; q < G_; q++) {
    double av = fabs(Zb[(size_t)q*N_ + n]);
    if (av > best) { best = av; bi = q; }
  }
  belong[idx] = bi;
}

// -------- K10: NMS + quota scheduling + index emission (one block per batch) --------
__global__ __launch_bounds__(256) void k_nms(const float* __restrict__ sim,
    const float* __restrict__ cls, const int* __restrict__ belong,
    const float* __restrict__ thrF,
    float* __restrict__ ns, float* __restrict__ rs, float* __restrict__ outF) {
  __shared__ int sel[G_];
  __shared__ int kc[G_], gc[G_], lowv[G_], upv[G_], tokd[G_], sortg[G_], pre[G_ + 1];
  __shared__ int gathered[L_];
  __shared__ int bl_s[N_];
  __shared__ float cls_s[N_];
  __shared__ int anyv;
  int b = blockIdx.x, tid = threadIdx.x;
  const float* simb = sim + (size_t)b*N_*N_;
  float* nsb = ns + (size_t)b*N_*G_;
  float* rsb = rs + (size_t)b*N_*G_;
  float thr = thrF[b];
  for (int i = tid; i < N_; i += 256) { bl_s[i] = belong[b*N_ + i]; cls_s[i] = cls[b*N_ + i]; }
  if (tid < G_) gc[tid] = 0;
  __syncthreads();
  for (int i = tid; i < N_; i += 256) atomicAdd(&gc[bl_s[i]], 1);
  for (int idx = tid; idx < N_ * G_; idx += 256) {
    int n = idx / G_, g = idx % G_;
    float sc = (bl_s[n] == g) ? cls_s[n] : 0.0f;
    nsb[idx] = sc; rsb[idx] = sc;
  }
  __syncthreads();
  // ---- NMS ----
  float gs = 1000.0f;
  int myc = 0;
  for (int iter = 0; iter < 640; iter++) {
    if (tid == 0) anyv = 0;
    __syncthreads();
    if (tid < G_) {
      float mx = 0.0f; int mi = -1;
      for (int n = 0; n < N_; n++) {
        float vv = nsb[n*G_ + tid];
        if (vv > mx) { mx = vv; mi = n; }
      }
      sel[tid] = mi;
      if (mi >= 0) anyv = 1;
    }
    __syncthreads();
    if (!anyv) break;
    if (tid < G_ && sel[tid] >= 0) {
      int m = sel[tid];
      rsb[m*G_ + tid] = gs;
      nsb[m*G_ + tid] = 0.0f;
      const float* srow = simb + (size_t)m*N_;
      for (int n = 0; n < N_; n++) {
        if (nsb[n*G_ + tid] > 0.0f && srow[n] > thr) nsb[n*G_ + tid] = 0.0f;
      }
      myc++;
    }
    gs -= 1.0f;
    __syncthreads();
  }
  if (tid < G_) kc[tid] = myc;
  __syncthreads();
  // ---- scheduling (scalar, matches reference loop semantics) ----
  if (tid == 0) {
    int sumkc = 0; for (int g = 0; g < G_; g++) sumkc += kc[g];
    int sumlow = 0;
    for (int g = 0; g < G_; g++) {
      lowv[g] = (gc[g] < 1) ? gc[g] : 1;
      int u = 15; if (gc[g] < u) u = gc[g]; if (kc[g] < u) u = kc[g];
      upv[g] = u; sumlow += lowv[g];
    }
    int su = 0; for (int g = 0; g < G_; g++) su += upv[g];
    while (su < NEED_) {
      su = 0;
      for (int g = 0; g < G_; g++) { int u = upv[g] + 1; if (u > gc[g]) u = gc[g]; upv[g] = u; su += u; }
    }
    int other = NEED_ - sumlow - 1; if (other < 0) other = 0;
    float s = (float)sumkc;
    float c = 0.0f; int prevR = 0;
    float otherf = (float)other;
    for (int g = 0; g < G_; g++) {
      float nc = (float)kc[g] / s;
      c += nc;
      int R = (int)rintf(c * otherf);          // round half-to-even like jnp.round
      int od = R - prevR; prevR = R;
      int t0 = od + lowv[g]; if (t0 > upv[g]) t0 = upv[g];
      tokd[g] = t0;
    }
    for (int g = 0; g < G_; g++) sortg[g] = g;
    for (int a = 1; a < G_; a++) {            // stable insertion sort, kc descending
      int vIdx = sortg[a]; int key = kc[vIdx]; int p2 = a - 1;
      while (p2 >= 0 && kc[sortg[p2]] < key) { sortg[p2+1] = sortg[p2]; p2--; }
      sortg[p2+1] = vIdx;
    }
    int target = other + sumlow;
    int sumd = 0; for (int g = 0; g < G_; g++) sumd += tokd[g];
    int fg = 0;
    while (sumd < target) {
      int gi = sortg[(fg < G_-1) ? fg : (G_-1)];
      int fill = upv[gi] - tokd[gi];
      int rem = target - sumd;
      if (rem < fill) fill = rem;
      tokd[gi] += fill; sumd += fill;
      fg++;
      if (fg > 100000) break;
    }
    pre[0] = 0; for (int g = 0; g < G_; g++) pre[g+1] = pre[g] + tokd[g];
  }
  __syncthreads();
  for (int i = tid; i < L_; i += 256) gathered[i] = 0;
  __syncthreads();
  // ---- per-group prefix selection (repeated first-max == stable argsort prefix) ----
  if (tid < G_) {
    int g = tid;
    int td = tokd[g], base = pre[g];
    for (int t = 0; t < td; t++) {
      float bv = -3e38f; int bn2 = 0;
      for (int n = 0; n < N_; n++) {
        float vv = rsb[n*G_ + g];
        if (vv > bv) { bv = vv; bn2 = n; }
      }
      rsb[bn2*G_ + g] = -3e38f;
      int pos = base + t;
      if (pos < L_) gathered[pos] = bn2;
    }
  }
  __syncthreads();
  if (tid < NEED_) {
    float val = (tid == 0) ? 0.0f : (float)(gathered[tid - 1] + 1);
    outF[(size_t)B_*NEED_*D_ + (size_t)b*NEED_ + tid] = val;
  }
}

// -------- K11: gather selected hidden rows --------
__global__ void k_gather(const float* __restrict__ hs, float* __restrict__ outF) {
  int blk = blockIdx.x;
  int b = blk / NEED_, i = blk % NEED_;
  int idx = (int)outF[(size_t)B_*NEED_*D_ + (size_t)b*NEED_ + i];
  const float4* src = (const float4*)(hs + ((size_t)b*T_ + idx) * (size_t)D_);
  float4* dst = (float4*)(outF + ((size_t)b*NEED_ + i) * (size_t)D_);
  dst[threadIdx.x] = src[threadIdx.x];
}

extern "C" void kernel_launch(void* const* d_in, const int* in_sizes, int n_in,
                              void* d_out, int out_size, void* d_ws, size_t ws_size,
                              hipStream_t stream) {
  if (ws_size < WS_NEEDED) return;  // avoid corrupting memory if scratch too small
  const float* hs   = (const float*)d_in[0];
  const float* attn = (const float*)d_in[1];
  float* outF = (float*)d_out;
  char* w = (char*)d_ws;
  float*  msig = (float*)(w + OF_MSIG);
  float*  sim  = (float*)(w + OF_SIM);
  double* A    = (double*)(w + OF_A);
  double* ms   = (double*)(w + OF_MS);
  double* invn = (double*)(w + OF_INVN);
  float*  cls  = (float*)(w + OF_CLS);
  double* dT   = (double*)(w + OF_DT);
  double* eT   = (double*)(w + OF_ET);
  double* tauT = (double*)(w + OF_TAU);
  double* eval = (double*)(w + OF_EVAL);
  double* Z    = (double*)(w + OF_Z);
  float*  ns   = (float*)(w + OF_NS);
  float*  rs   = (float*)(w + OF_RS);
  double* part = (double*)(w + OF_PART);
  float*  thrF = (float*)(w + OF_THR);
  int*    belong = (int*)(w + OF_BEL);
  // inverse-iteration scratch aliases msig region (msig dead after the Gram GEMM)
  double* Ud = (double*)(w + OF_MSIG);
  double* U1 = Ud + (size_t)B_*N_*G_;
  double* U2 = U1 + (size_t)B_*N_*G_;
  double* Um = U2 + (size_t)B_*N_*G_;
  double* Yv = Um + (size_t)B_*N_*G_;
  int*    Ufl = (int*)(Yv + (size_t)B_*N_*G_);

  k_prep<<<B_*N_, 256, 0, stream>>>(hs, msig, ms, invn);
  k_cls<<<(B_*N_ + 255)/256, 256, 0, stream>>>(attn, cls);
  k_gemm<<<dim3(N_/32, N_/32, B_), 256, 0, stream>>>(hs, msig, ms, invn, A, sim, 0);
  k_gemm<<<dim3(N_/32, N_/32, B_), 256, 0, stream>>>(hs, msig, ms, invn, A, sim, 1);
  k_simsum<<<B_*36, 256, 0, stream>>>(sim, part);
  k_thr<<<1, 64, 0, stream>>>(part, thrF);
  k_tridiag<<<B_, 1024, 0, stream>>>(A, dT, eT, tauT);
  k_eigvals<<<B_, 64, 0, stream>>>(dT, eT, eval);
  k_eigvecs<<<B_, 64, 0, stream>>>(dT, eT, eval, Ud, U1, U2, Um, Ufl, Yv, Z);
  k_backxf<<<B_, 1024, 0, stream>>>(A, tauT, Z);
  k_belong<<<(B_*N_ + 255)/256, 256, 0, stream>>>(Z, belong);
  k_nms<<<B_, 256, 0, stream>>>(sim, cls, belong, thrF, ns, rs, outF);
  k_gather<<<B_*NEED_, 256, 0, stream>>>(hs, outF);
}

// Round 2
// 14797.444 us; speedup vs baseline: 2.5024x; 2.5024x over previous
//
#include <hip/hip_runtime.h>
#include <math.h>

// Problem constants
constexpr int B_ = 4, T_ = 577, N_ = 576, D_ = 1024, G_ = 48, H_ = 16;
constexpr int NEED_ = 192, L_ = 191;
constexpr int TRIU_CNT = N_ * (N_ - 1) / 2; // 165600
constexpr int NB_ = 16;                     // blocks per batch in tridiag
constexpr int NBAR_ = 2400;                 // barrier slots per batch

// ---------------- workspace layout (bytes) ----------------
constexpr size_t OF_MSIG = 0;                                    // f32 B*N*D (aliased by invit solver scratch later)
constexpr size_t OF_SIM  = OF_MSIG + (size_t)B_*N_*D_*4;
constexpr size_t OF_A    = OF_SIM  + (size_t)B_*N_*N_*4;         // f64 Gram (also holds Householder vectors in rows)
constexpr size_t OF_MS   = OF_A    + (size_t)B_*N_*N_*8;         // f64 sigmoid row sums
constexpr size_t OF_INVN = OF_MS   + (size_t)B_*N_*8;            // f64 1/norm of raw hs rows
constexpr size_t OF_CLS  = OF_INVN + (size_t)B_*N_*8;            // f32 cls attention sums
constexpr size_t OF_DT   = OF_CLS  + (size_t)B_*N_*4;            // f64 tridiag diagonal
constexpr size_t OF_ET   = OF_DT   + (size_t)B_*N_*8;            // f64 tridiag off-diagonal
constexpr size_t OF_TAU  = OF_ET   + (size_t)B_*N_*8;            // f64 Householder taus
constexpr size_t OF_EVAL = OF_TAU  + (size_t)B_*N_*8;            // f64 top-48 eigenvalues (descending)
constexpr size_t OF_Z    = OF_EVAL + (size_t)B_*G_*8;            // f64 eigenvectors [b][q][i]
constexpr size_t OF_PART = OF_Z    + (size_t)B_*G_*N_*8;         // f64 simmean partials B*36
constexpr size_t OF_THR  = OF_PART + (size_t)B_*36*8;            // f32 thresholds (padded)
constexpr size_t OF_BEL  = OF_THR  + 64;                         // int belong
constexpr size_t OF_BAR  = OF_BEL  + (size_t)B_*N_*4;            // int barrier counters
constexpr size_t OF_VB   = OF_BAR  + (size_t)B_*NBAR_*4;         // f64 vbuf (row-k publish)
constexpr size_t OF_WB   = OF_VB   + (size_t)B_*N_*8;            // f64 wbuf (w publish)
constexpr size_t WS_NEEDED = OF_WB + (size_t)B_*N_*8;

__device__ __forceinline__ double blockReduceD(double x, double* red) {
  int lane = threadIdx.x & 63, wv = threadIdx.x >> 6;
  int nw = (blockDim.x + 63) >> 6;
  for (int o = 32; o > 0; o >>= 1) x += __shfl_down(x, o);
  __syncthreads();                // protect red from previous use
  if (lane == 0) red[wv] = x;
  __syncthreads();
  double t = red[0];
  for (int i = 1; i < nw; i++) t += red[i];
  return t;                       // same deterministic value on all threads/blocks
}

// coherent (agent-scope, cache-bypassing) load/store for cross-block data
__device__ __forceinline__ double cload(const double* p) {
  return __hip_atomic_load(p, __ATOMIC_RELAXED, __HIP_MEMORY_SCOPE_AGENT);
}
__device__ __forceinline__ void cstore(double* p, double x) {
  __hip_atomic_store(p, x, __ATOMIC_RELAXED, __HIP_MEMORY_SCOPE_AGENT);
}

// device barrier among the NB_ blocks of one batch (monotone counter per use)
__device__ __forceinline__ void gbar(int* bar, int& barNo, int tid) {
  __syncthreads();
  if (tid == 0) {
    __threadfence();
    atomicAdd(&bar[barNo], 1);
    while (__hip_atomic_load(&bar[barNo], __ATOMIC_ACQUIRE, __HIP_MEMORY_SCOPE_AGENT) < NB_)
      __builtin_amdgcn_s_sleep(1);
  }
  __syncthreads();
  barNo++;
}

// -------- K1: sigmoid features, row sums, inverse norms (+ zero barrier slots) --------
__global__ void k_prep(const float* __restrict__ hs, float* __restrict__ msig,
                       double* __restrict__ ms, double* __restrict__ invn,
                       int* __restrict__ bars) {
  __shared__ double red[16];
  if (blockIdx.x == 0) {
    for (int i = threadIdx.x; i < B_ * NBAR_; i += blockDim.x) bars[i] = 0;
  }
  int bn = blockIdx.x; int b = bn / N_, n = bn % N_;
  const float* row = hs + ((size_t)b*T_ + (n+1)) * (size_t)D_;
  float* mrow = msig + (size_t)bn * D_;
  double ssig = 0.0, ssq = 0.0;
  for (int d = threadIdx.x; d < D_; d += blockDim.x) {
    float x = row[d];
    float sg = 1.0f / (1.0f + expf(-x));
    mrow[d] = sg;
    ssig += (double)sg;
    ssq  += (double)x * (double)x;
  }
  double tot_sig = blockReduceD(ssig, red);
  double tot_sq  = blockReduceD(ssq, red);
  if (threadIdx.x == 0) {
    ms[bn] = tot_sig;
    invn[bn] = 1.0 / fmax(sqrt(tot_sq), 1e-12);
  }
}

// -------- K2: cls attention sums --------
__global__ void k_cls(const float* __restrict__ attn, float* __restrict__ cls) {
  int idx = blockIdx.x * blockDim.x + threadIdx.x;
  if (idx >= B_ * N_) return;
  int b = idx / N_, n = idx % N_;
  float s = 0.0f;
  for (int h = 0; h < H_; h++)
    s += attn[(((size_t)b*H_ + h) * T_ + 0) * T_ + (1 + n)];
  cls[idx] = s;
}

// -------- K3: tiled X*X^T GEMM; mode0 -> Gram (f64), mode1 -> cosine sim (f32) --------
__global__ void k_gemm(const float* __restrict__ hs, const float* __restrict__ msig,
                       const double* __restrict__ ms, const double* __restrict__ invn,
                       double* __restrict__ Aout, float* __restrict__ sim, int mode) {
  __shared__ float As[32][17], Bs[32][17];
  int b = blockIdx.z;
  int bi0 = blockIdx.y * 32, bj0 = blockIdx.x * 32;
  const float* base = (mode == 0) ? (msig + (size_t)b*N_*D_)
                                  : (hs + ((size_t)b*T_ + 1) * (size_t)D_);
  int tid = threadIdx.x;
  int tx = tid & 15, ty = tid >> 4;
  double a00 = 0, a01 = 0, a10 = 0, a11 = 0;
  for (int k0 = 0; k0 < D_; k0 += 16) {
    int r = tid >> 4, c = tid & 15;
    As[r][c] = base[(size_t)(bi0 + r) * D_ + k0 + c];
    Bs[r][c] = base[(size_t)(bj0 + r) * D_ + k0 + c];
    int e = tid + 256; r = e >> 4; c = e & 15;
    As[r][c] = base[(size_t)(bi0 + r) * D_ + k0 + c];
    Bs[r][c] = base[(size_t)(bj0 + r) * D_ + k0 + c];
    __syncthreads();
#pragma unroll
    for (int kk = 0; kk < 16; kk++) {
      double x0 = As[2*ty][kk],   x1 = As[2*ty+1][kk];
      double y0 = Bs[2*tx][kk],   y1 = Bs[2*tx+1][kk];
      a00 += x0*y0; a01 += x0*y1; a10 += x1*y0; a11 += x1*y1;
    }
    __syncthreads();
  }
  int i0 = bi0 + 2*ty, j0 = bj0 + 2*tx;
  if (mode == 0) {
    const double* msb = ms + (size_t)b*N_;
    double* Ab = Aout + (size_t)b*N_*N_;
    const double inv1024 = 1.0 / 1024.0;
    Ab[(size_t)i0*N_ + j0]         = a00 - msb[i0]*msb[j0]*inv1024;
    Ab[(size_t)i0*N_ + j0+1]       = a01 - msb[i0]*msb[j0+1]*inv1024;
    Ab[(size_t)(i0+1)*N_ + j0]     = a10 - msb[i0+1]*msb[j0]*inv1024;
    Ab[(size_t)(i0+1)*N_ + j0+1]   = a11 - msb[i0+1]*msb[j0+1]*inv1024;
  } else {
    const double* iv = invn + (size_t)b*N_;
    float* sb = sim + (size_t)b*N_*N_;
    sb[(size_t)i0*N_ + j0]       = (float)(a00 * iv[i0]*iv[j0]);
    sb[(size_t)i0*N_ + j0+1]     = (float)(a01 * iv[i0]*iv[j0+1]);
    sb[(size_t)(i0+1)*N_ + j0]   = (float)(a10 * iv[i0+1]*iv[j0]);
    sb[(size_t)(i0+1)*N_ + j0+1] = (float)(a11 * iv[i0+1]*iv[j0+1]);
  }
}

// -------- K4: upper-triangle sum partials --------
__global__ void k_simsum(const float* __restrict__ sim, double* __restrict__ part) {
  __shared__ double red[4];
  int blk = blockIdx.x; int b = blk / 36, s = blk % 36;
  const float* sb = sim + (size_t)b*N_*N_;
  double p = 0.0;
  for (int i = s*16; i < s*16 + 16; i++) {
    const float* row = sb + (size_t)i*N_;
    for (int j = i + 1 + threadIdx.x; j < N_; j += blockDim.x) p += (double)row[j];
  }
  double t = blockReduceD(p, red);
  if (threadIdx.x == 0) part[blk] = t;
}

__global__ void k_thr(const double* __restrict__ part, float* __restrict__ thrF) {
  int b = threadIdx.x;
  if (b < B_) {
    double s = 0.0;
    for (int i = 0; i < 36; i++) s += part[b*36 + i];
    thrF[b] = 6.0f * (float)(s / (double)TRIU_CNT);
  }
}

// -------- K5: multi-block Householder tridiagonalization --------
// 16 blocks per batch, cyclic row ownership (row r -> block r % NB_).
// Cross-block data (row k, w vector) moves through coherent vbuf/wbuf;
// scalars (sigma, tau, K) are recomputed redundantly & deterministically.
__global__ __launch_bounds__(256) void k_tridiag_mb(double* __restrict__ Aall,
    double* __restrict__ dT, double* __restrict__ eT, double* __restrict__ tauT,
    double* __restrict__ vb_all, double* __restrict__ wb_all, int* __restrict__ bars) {
  __shared__ double v[N_], w[N_];
  __shared__ double red[4];
  int blk = blockIdx.x;
  int b = blk % B_;          // batch: clusters each batch's blocks on 2 XCDs
  int t = blk / B_;          // 0..NB_-1
  double* A  = Aall + (size_t)b*N_*N_;
  double* dv = dT   + (size_t)b*N_;
  double* ev = eT   + (size_t)b*N_;
  double* tv = tauT + (size_t)b*N_;
  double* vb = vb_all + (size_t)b*N_;
  double* wb = wb_all + (size_t)b*N_;
  int* bar = bars + b*NBAR_;
  int tid = threadIdx.x, lane = tid & 63, wv = tid >> 6;
  int barNo = 0;
  for (int k = 0; k < N_ - 2; k++) {
    // ---- phase 1: everyone loads row k, computes sigma/alpha/tau identically ----
    double ps = 0.0;
    if (k == 0) {
      for (int j = 1 + tid; j < N_; j += 256) { double x = A[j]; v[j] = x; ps += x * x; }
    } else {
      for (int j = k + 1 + tid; j < N_; j += 256) { double x = cload(&vb[j]); v[j] = x; ps += x * x; }
    }
    double sigma = blockReduceD(ps, red);
    double x0 = v[k + 1];
    double alpha, tauk;
    if (sigma == 0.0) { alpha = 0.0; tauk = 0.0; }
    else {
      alpha = (x0 >= 0.0) ? -sqrt(sigma) : sqrt(sigma);
      tauk = 1.0 / (sigma - alpha * x0);
    }
    __syncthreads();
    if (tid == 0) v[k + 1] = x0 - alpha;
    __syncthreads();
    if ((k % NB_) == t) {              // owner of row k archives reflector + d/e/tau
      if (tid == 0) { dv[k] = A[(size_t)k*N_ + k]; ev[k] = alpha; tv[k] = tauk; }
      for (int j = k + 1 + tid; j < N_; j += 256) A[(size_t)k*N_ + j] = v[j];
    }
    int rem = (t - ((k + 1) % NB_)) % NB_; if (rem < 0) rem += NB_;
    int r0 = k + 1 + rem;              // first owned row > k
    if (tauk != 0.0) {
      // ---- phase 2: w[r] = tau * A[r,:] . v for owned rows ----
      for (int r = r0 + wv*NB_; r < N_; r += 4*NB_) {
        const double* Ar = A + (size_t)r*N_;
        double pd = 0.0;
        for (int j = k + 1 + lane; j < N_; j += 64) pd += Ar[j] * v[j];
        for (int o = 32; o > 0; o >>= 1) pd += __shfl_down(pd, o);
        if (lane == 0) cstore(&wb[r], tauk * pd);
      }
      gbar(bar, barNo, tid);
      // ---- phase 3: assemble w, K redundantly; rank-2 update owned rows ----
      double pk = 0.0;
      for (int i = k + 1 + tid; i < N_; i += 256) { double wi = cload(&wb[i]); w[i] = wi; pk += v[i] * wi; }
      double vtp = blockReduceD(pk, red);
      double K = 0.5 * tauk * vtp;
      for (int i = k + 1 + tid; i < N_; i += 256) w[i] -= K * v[i];
      __syncthreads();
      for (int r = r0 + wv*NB_; r < N_; r += 4*NB_) {
        double vr = v[r], wr = w[r];
        double* Ar = A + (size_t)r*N_;
        for (int j = k + 1 + lane; j < N_; j += 64) Ar[j] -= vr * w[j] + wr * v[j];
      }
      __syncthreads();
      if (((k + 1) % NB_) == t) {      // owner publishes next pivot row
        for (int j = k + 2 + tid; j < N_; j += 256) cstore(&vb[j], A[(size_t)(k+1)*N_ + j]);
      }
      gbar(bar, barNo, tid);
    } else {
      __syncthreads();
      if (((k + 1) % NB_) == t) {
        for (int j = k + 2 + tid; j < N_; j += 256) cstore(&vb[j], A[(size_t)(k+1)*N_ + j]);
      }
      gbar(bar, barNo, tid);
    }
  }
  if (t == ((N_-2) % NB_) && tid == 0) {
    dv[N_-2] = A[(size_t)(N_-2)*N_ + (N_-2)];
    ev[N_-2] = A[(size_t)(N_-2)*N_ + (N_-1)];
  }
  if (t == ((N_-1) % NB_) && tid == 0) dv[N_-1] = A[(size_t)(N_-1)*N_ + (N_-1)];
  if (t == 0 && tid == 0) { ev[N_-1] = 0.0; tv[N_-2] = 0.0; tv[N_-1] = 0.0; }
}

// -------- K6: top-48 eigenvalues by Sturm bisection (lane per eigenvalue) --------
__global__ void k_eigvals(const double* __restrict__ dT, const double* __restrict__ eT,
                          double* __restrict__ eval) {
  __shared__ double sd[N_], se[N_];
  int b = blockIdx.x;
  for (int i = threadIdx.x; i < N_; i += blockDim.x) {
    sd[i] = dT[(size_t)b*N_ + i];
    se[i] = eT[(size_t)b*N_ + i];
  }
  __syncthreads();
  int j = threadIdx.x;
  if (j < G_) {
    double lo = 1e300, hi = -1e300;
    for (int i = 0; i < N_; i++) {
      double r = ((i > 0) ? fabs(se[i-1]) : 0.0) + ((i < N_-1) ? fabs(se[i]) : 0.0);
      lo = fmin(lo, sd[i] - r); hi = fmax(hi, sd[i] + r);
    }
    double span = hi - lo + 1e-30;
    lo -= span * 1e-6; hi += span * 1e-6;
    int target = N_ - 1 - j;  // ascending index of j-th largest
    const double PIV = 1e-280;
    for (int it = 0; it < 80; it++) {
      double mid = 0.5 * (lo + hi);
      int cnt = 0;
      double q = sd[0] - mid;
      if (q <= PIV) { cnt++; q = fmin(q, -PIV); }
      for (int i = 1; i < N_; i++) {
        q = (sd[i] - mid) - se[i-1]*se[i-1] / q;
        if (q <= PIV) { cnt++; q = fmin(q, -PIV); }
      }
      if (cnt > target) hi = mid; else lo = mid;
    }
    eval[(size_t)b*G_ + j] = 0.5 * (lo + hi);
  }
}

// -------- K7: inverse iteration (lane per eigenvector) + rare cluster re-orth --------
__global__ void k_eigvecs(const double* __restrict__ dT, const double* __restrict__ eT,
    const double* __restrict__ eval,
    double* __restrict__ Ud, double* __restrict__ U1, double* __restrict__ U2,
    double* __restrict__ Um, int* __restrict__ Ufl, double* __restrict__ Yv,
    double* __restrict__ Z) {
  __shared__ double sd[N_], se[N_];
  __shared__ double red0;
  __shared__ int cstart[G_];
  __shared__ double sh_ev[G_];
  int b = blockIdx.x;
  for (int i = threadIdx.x; i < N_; i += blockDim.x) {
    sd[i] = dT[(size_t)b*N_ + i]; se[i] = eT[(size_t)b*N_ + i];
  }
  if (threadIdx.x < G_) sh_ev[threadIdx.x] = eval[(size_t)b*G_ + threadIdx.x];
  __syncthreads();
  int j = threadIdx.x;
  size_t sbase = (size_t)b * N_ * G_;
  double* ud = Ud + sbase; double* u1 = U1 + sbase; double* u2 = U2 + sbase;
  double* um = Um + sbase; int* ufl = Ufl + sbase; double* yv = Yv + sbase;
  if (j < G_) {
    double lam = sh_ev[j];
    double GU = 1e-30 * (1.0 + fabs(lam));
    double ak = sd[0] - lam;
    double bk = se[0];
    for (int k = 0; k < N_ - 1; k++) {
      double sub = se[k];
      double diag1 = sd[k+1] - lam;
      double sup1 = (k < N_ - 2) ? se[k+1] : 0.0;
      double udv, u1v, u2v, umv; int flv;
      if (fabs(ak) >= fabs(sub)) {
        double piv = ak;
        if (fabs(piv) < GU) piv = (piv >= 0.0) ? GU : -GU;
        double ml = sub / piv;
        udv = piv; u1v = bk; u2v = 0.0; umv = ml; flv = 0;
        ak = diag1 - ml * bk; bk = sup1;
      } else {
        double ml = ak / sub;
        udv = sub; u1v = diag1; u2v = sup1; umv = ml; flv = 1;
        ak = bk - ml * diag1; bk = -ml * sup1;
      }
      ud[(size_t)k*G_+j] = udv; u1[(size_t)k*G_+j] = u1v; u2[(size_t)k*G_+j] = u2v;
      um[(size_t)k*G_+j] = umv; ufl[(size_t)k*G_+j] = flv;
    }
    { double piv = ak; if (fabs(piv) < GU) piv = (piv >= 0.0) ? GU : -GU;
      ud[(size_t)(N_-1)*G_+j] = piv; u1[(size_t)(N_-1)*G_+j] = 0.0; u2[(size_t)(N_-1)*G_+j] = 0.0; }
    for (int i = 0; i < N_; i++) {
      unsigned s = (unsigned)(i * 2654435761u) ^ (unsigned)((j + 1) * 40503u) ^ (unsigned)(b * 2246822519u);
      s = s * 1664525u + 1013904223u;
      s ^= s >> 16; s = s * 2246822519u;
      double rv = ((double)(s >> 8) * (1.0 / 16777216.0)) * 2.0 - 1.0;
      if (fabs(rv) < 1e-3) rv = 0.5;
      yv[(size_t)i*G_+j] = rv;
    }
    for (int it = 0; it < 3; it++) {
      if (it) {
        double mx = 0.0;
        for (int i = 0; i < N_; i++) mx = fmax(mx, fabs(yv[(size_t)i*G_+j]));
        double sc = 1.0 / fmax(mx, 1e-300);
        for (int i = 0; i < N_; i++) yv[(size_t)i*G_+j] *= sc;
      }
      for (int k = 0; k < N_ - 1; k++) {
        double yk = yv[(size_t)k*G_+j], yk1 = yv[(size_t)(k+1)*G_+j];
        if (ufl[(size_t)k*G_+j]) { double tt = yk; yk = yk1; yk1 = tt; }
        yk1 -= um[(size_t)k*G_+j] * yk;
        yv[(size_t)k*G_+j] = yk; yv[(size_t)(k+1)*G_+j] = yk1;
      }
      double y1, y2 = 0.0;
      { double tt = yv[(size_t)(N_-1)*G_+j] / ud[(size_t)(N_-1)*G_+j];
        yv[(size_t)(N_-1)*G_+j] = tt; y1 = tt; }
      for (int k = N_ - 2; k >= 0; k--) {
        double tt = yv[(size_t)k*G_+j] - u1[(size_t)k*G_+j]*y1 - u2[(size_t)k*G_+j]*y2;
        tt /= ud[(size_t)k*G_+j];
        yv[(size_t)k*G_+j] = tt;
        y2 = y1; y1 = tt;
      }
    }
    double s2 = 0.0;
    for (int i = 0; i < N_; i++) { double tt = yv[(size_t)i*G_+j]; s2 += tt * tt; }
    double inv = 1.0 / sqrt(fmax(s2, 1e-300));
    double* Zj = Z + ((size_t)b*G_ + j) * N_;
    for (int i = 0; i < N_; i++) Zj[i] = yv[(size_t)i*G_+j] * inv;
  }
  __syncthreads();
  if (threadIdx.x == 0) {
    double tol = 1e-10 * (fabs(sh_ev[0]) + 1.0);
    cstart[0] = 0;
    for (int q = 1; q < G_; q++)
      cstart[q] = ((sh_ev[q-1] - sh_ev[q]) < tol) ? cstart[q-1] : q;
  }
  __syncthreads();
  for (int q = 1; q < G_; q++) {
    if (cstart[q] == q) continue;
    double* Zq = Z + ((size_t)b*G_ + q) * N_;
    for (int p = cstart[q]; p < q; p++) {
      double* Zp = Z + ((size_t)b*G_ + p) * N_;
      double dp = 0.0;
      for (int i = threadIdx.x; i < N_; i += blockDim.x) dp += Zq[i] * Zp[i];
      for (int o = 32; o > 0; o >>= 1) dp += __shfl_down(dp, o);
      if (threadIdx.x == 0) red0 = dp;
      __syncthreads();
      double dd = red0;
      for (int i = threadIdx.x; i < N_; i += blockDim.x) Zq[i] -= dd * Zp[i];
      __syncthreads();
    }
    double s2 = 0.0;
    for (int i = threadIdx.x; i < N_; i += blockDim.x) { double tt = Zq[i]; s2 += tt * tt; }
    for (int o = 32; o > 0; o >>= 1) s2 += __shfl_down(s2, o);
    if (threadIdx.x == 0) red0 = s2;
    __syncthreads();
    double inv = 1.0 / sqrt(fmax(red0, 1e-300));
    for (int i = threadIdx.x; i < N_; i += blockDim.x) Zq[i] *= inv;
    __syncthreads();
  }
}

// -------- K8: back-transform, one wave per (batch, eigenvector), Z in registers --------
__global__ __launch_bounds__(64) void k_backxf_mb(const double* __restrict__ Aall,
    const double* __restrict__ tauT, double* __restrict__ Z) {
  int blk = blockIdx.x;
  int b = blk / G_, q = blk % G_;
  const double* A = Aall + (size_t)b*N_*N_;
  const double* tau = tauT + (size_t)b*N_;
  double* Zq = Z + ((size_t)b*G_ + q) * N_;
  int lane = threadIdx.x;
  double z[9];
#pragma unroll
  for (int m = 0; m < 9; m++) z[m] = Zq[lane + 64*m];
  for (int k = N_ - 3; k >= 0; k--) {
    double t = tau[k];
    if (t == 0.0) continue;
    const double* vk = A + (size_t)k*N_;
    double vv[9]; double p = 0.0;
#pragma unroll
    for (int m = 0; m < 9; m++) {
      int i = lane + 64*m;
      double vi = (i > k) ? vk[i] : 0.0;
      vv[m] = vi; p += vi * z[m];
    }
    for (int o = 32; o > 0; o >>= 1) p += __shfl_down(p, o);
    p = __shfl(p, 0);
    double s = t * p;
#pragma unroll
    for (int m = 0; m < 9; m++) z[m] -= s * vv[m];
  }
#pragma unroll
  for (int m = 0; m < 9; m++) Zq[lane + 64*m] = z[m];
}

// -------- K9: belong = argmax_q |V[n][q]| (first max) --------
__global__ void k_belong(const double* __restrict__ Z, int* __restrict__ belong) {
  int idx = blockIdx.x * blockDim.x + threadIdx.x;
  if (idx >= B_ * N_) return;
  int b = idx / N_, n = idx % N_;
  const double* Zb = Z + (size_t)b*G_*N_;
  double best = -1.0; int bi = 0;
  for (int q = 0; q < G_; q++) {
    double av = fabs(Zb[(size_t)q*N_ + n]);
    if (av > best) { best = av; bi = q; }
  }
  belong[idx] = bi;
}

// -------- K10: NMS + quota scheduling + index emission (one block per batch) --------
// Uses per-group compacted token lists; scores live in LDS indexed by token
// (each token belongs to exactly one group, so per-token storage suffices).
__global__ __launch_bounds__(256) void k_nms(const float* __restrict__ sim,
    const float* __restrict__ cls, const int* __restrict__ belong,
    const float* __restrict__ thrF, float* __restrict__ outF) {
  __shared__ float nsv[N_], rsv[N_];
  __shared__ int bl_s[N_];
  __shared__ int lists[N_];
  __shared__ int off[G_ + 1];
  __shared__ int kc[G_], gc[G_], lowv[G_], upv[G_], tokd[G_], sortg[G_], pre[G_ + 1];
  __shared__ int gathered[L_];
  __shared__ int anyv;
  __shared__ float shthr;
  int b = blockIdx.x, tid = threadIdx.x;
  const float* simb = sim + (size_t)b*N_*N_;
  if (tid == 0) shthr = thrF[b];
  if (tid < G_) gc[tid] = 0;
  __syncthreads();
  for (int i = tid; i < N_; i += 256) {
    int g = belong[b*N_ + i];
    bl_s[i] = g;
    float sc = cls[b*N_ + i];
    nsv[i] = sc; rsv[i] = sc;
    atomicAdd(&gc[g], 1);
  }
  __syncthreads();
  if (tid == 0) {           // deterministic (ascending-n) group list build
    off[0] = 0;
    for (int g = 0; g < G_; g++) off[g+1] = off[g] + gc[g];
    for (int g = 0; g < G_; g++) pre[g] = off[g];
    for (int n = 0; n < N_; n++) lists[pre[bl_s[n]]++] = n;
  }
  __syncthreads();
  float thr = shthr;
  // ---- NMS ----
  float gs = 1000.0f;
  int myc = 0;
  for (int iter = 0; iter < N_ + 8; iter++) {
    if (tid == 0) anyv = 0;
    __syncthreads();
    int m = -1;
    if (tid < G_) {
      float mx = 0.0f;
      for (int a = off[tid]; a < off[tid+1]; a++) {
        int n2 = lists[a];
        float vv = nsv[n2];
        if (vv > mx) { mx = vv; m = n2; }
      }
      if (m >= 0) anyv = 1;
    }
    __syncthreads();
    if (m >= 0) {
      rsv[m] = gs;
      nsv[m] = 0.0f;
      const float* srow = simb + (size_t)m*N_;
      for (int a = off[tid]; a < off[tid+1]; a++) {
        int n2 = lists[a];
        if (nsv[n2] > 0.0f && srow[n2] > thr) nsv[n2] = 0.0f;
      }
      myc++;
    }
    gs -= 1.0f;
    __syncthreads();
    if (!anyv) break;
  }
  if (tid < G_) kc[tid] = myc;
  __syncthreads();
  // ---- scheduling (scalar, matches reference loop semantics) ----
  if (tid == 0) {
    int sumkc = 0; for (int g = 0; g < G_; g++) sumkc += kc[g];
    int sumlow = 0;
    for (int g = 0; g < G_; g++) {
      lowv[g] = (gc[g] < 1) ? gc[g] : 1;
      int u = 15; if (gc[g] < u) u = gc[g]; if (kc[g] < u) u = kc[g];
      upv[g] = u; sumlow += lowv[g];
    }
    int su = 0; for (int g = 0; g < G_; g++) su += upv[g];
    while (su < NEED_) {
      su = 0;
      for (int g = 0; g < G_; g++) { int u = upv[g] + 1; if (u > gc[g]) u = gc[g]; upv[g] = u; su += u; }
    }
    int other = NEED_ - sumlow - 1; if (other < 0) other = 0;
    float s = (float)sumkc;
    float c = 0.0f; int prevR = 0;
    float otherf = (float)other;
    for (int g = 0; g < G_; g++) {
      float nc = (float)kc[g] / s;
      c += nc;
      int R = (int)rintf(c * otherf);          // round half-to-even like jnp.round
      int od = R - prevR; prevR = R;
      int t0 = od + lowv[g]; if (t0 > upv[g]) t0 = upv[g];
      tokd[g] = t0;
    }
    for (int g = 0; g < G_; g++) sortg[g] = g;
    for (int a = 1; a < G_; a++) {            // stable insertion sort, kc descending
      int vIdx = sortg[a]; int key = kc[vIdx]; int p2 = a - 1;
      while (p2 >= 0 && kc[sortg[p2]] < key) { sortg[p2+1] = sortg[p2]; p2--; }
      sortg[p2+1] = vIdx;
    }
    int target = other + sumlow;
    int sumd = 0; for (int g = 0; g < G_; g++) sumd += tokd[g];
    int fg = 0;
    while (sumd < target) {
      int gi = sortg[(fg < G_-1) ? fg : (G_-1)];
      int fill = upv[gi] - tokd[gi];
      int rem = target - sumd;
      if (rem < fill) fill = rem;
      tokd[gi] += fill; sumd += fill;
      fg++;
      if (fg > 100000) break;
    }
    pre[0] = 0; for (int g = 0; g < G_; g++) pre[g+1] = pre[g] + tokd[g];
  }
  __syncthreads();
  for (int i = tid; i < L_; i += 256) gathered[i] = 0;
  __syncthreads();
  // ---- per-group prefix selection (repeated first-max == stable argsort prefix) ----
  if (tid < G_) {
    int g = tid;
    int td = tokd[g], base = pre[g];
    for (int t = 0; t < td; t++) {
      float bv = -3e38f; int bn2 = 0;
      for (int a = off[g]; a < off[g+1]; a++) {
        int n2 = lists[a];
        float vv = rsv[n2];
        if (vv > bv) { bv = vv; bn2 = n2; }
      }
      rsv[bn2] = -3e38f;
      int pos = base + t;
      if (pos < L_) gathered[pos] = bn2;
    }
  }
  __syncthreads();
  if (tid < NEED_) {
    float val = (tid == 0) ? 0.0f : (float)(gathered[tid - 1] + 1);
    outF[(size_t)B_*NEED_*D_ + (size_t)b*NEED_ + tid] = val;
  }
}

// -------- K11: gather selected hidden rows --------
__global__ void k_gather(const float* __restrict__ hs, float* __restrict__ outF) {
  int blk = blockIdx.x;
  int b = blk / NEED_, i = blk % NEED_;
  int idx = (int)outF[(size_t)B_*NEED_*D_ + (size_t)b*NEED_ + i];
  const float4* src = (const float4*)(hs + ((size_t)b*T_ + idx) * (size_t)D_);
  float4* dst = (float4*)(outF + ((size_t)b*NEED_ + i) * (size_t)D_);
  dst[threadIdx.x] = src[threadIdx.x];
}

extern "C" void kernel_launch(void* const* d_in, const int* in_sizes, int n_in,
                              void* d_out, int out_size, void* d_ws, size_t ws_size,
                              hipStream_t stream) {
  if (ws_size < WS_NEEDED) return;
  const float* hs   = (const float*)d_in[0];
  const float* attn = (const float*)d_in[1];
  float* outF = (float*)d_out;
  char* w = (char*)d_ws;
  float*  msig = (float*)(w + OF_MSIG);
  float*  sim  = (float*)(w + OF_SIM);
  double* A    = (double*)(w + OF_A);
  double* ms   = (double*)(w + OF_MS);
  double* invn = (double*)(w + OF_INVN);
  float*  cls  = (float*)(w + OF_CLS);
  double* dT   = (double*)(w + OF_DT);
  double* eT   = (double*)(w + OF_ET);
  double* tauT = (double*)(w + OF_TAU);
  double* eval = (double*)(w + OF_EVAL);
  double* Z    = (double*)(w + OF_Z);
  double* part = (double*)(w + OF_PART);
  float*  thrF = (float*)(w + OF_THR);
  int*    belong = (int*)(w + OF_BEL);
  int*    bars = (int*)(w + OF_BAR);
  double* vb   = (double*)(w + OF_VB);
  double* wb   = (double*)(w + OF_WB);
  // inverse-iteration scratch aliases msig region (msig dead after the Gram GEMM)
  double* Ud = (double*)(w + OF_MSIG);
  double* U1 = Ud + (size_t)B_*N_*G_;
  double* U2 = U1 + (size_t)B_*N_*G_;
  double* Um = U2 + (size_t)B_*N_*G_;
  double* Yv = Um + (size_t)B_*N_*G_;
  int*    Ufl = (int*)(Yv + (size_t)B_*N_*G_);

  k_prep<<<B_*N_, 256, 0, stream>>>(hs, msig, ms, invn, bars);
  k_cls<<<(B_*N_ + 255)/256, 256, 0, stream>>>(attn, cls);
  k_gemm<<<dim3(N_/32, N_/32, B_), 256, 0, stream>>>(hs, msig, ms, invn, A, sim, 0);
  k_gemm<<<dim3(N_/32, N_/32, B_), 256, 0, stream>>>(hs, msig, ms, invn, A, sim, 1);
  k_simsum<<<B_*36, 256, 0, stream>>>(sim, part);
  k_thr<<<1, 64, 0, stream>>>(part, thrF);
  k_tridiag_mb<<<B_*NB_, 256, 0, stream>>>(A, dT, eT, tauT, vb, wb, bars);
  k_eigvals<<<B_, 64, 0, stream>>>(dT, eT, eval);
  k_eigvecs<<<B_, 64, 0, stream>>>(dT, eT, eval, Ud, U1, U2, Um, Ufl, Yv, Z);
  k_backxf_mb<<<B_*G_, 64, 0, stream>>>(A, tauT, Z);
  k_belong<<<(B_*N_ + 255)/256, 256, 0, stream>>>(Z, belong);
  k_nms<<<B_, 256, 0, stream>>>(sim, cls, belong, thrF, outF);
  k_gather<<<B_*NEED_, 256, 0, stream>>>(hs, outF);
}

// Round 3
// 10459.180 us; speedup vs baseline: 3.5404x; 1.4148x over previous
//
#include <hip/hip_runtime.h>
#include <math.h>

// Problem constants
constexpr int B_ = 4, T_ = 577, N_ = 576, D_ = 1024, G_ = 48, H_ = 16;
constexpr int NEED_ = 192, L_ = 191;
constexpr int TRIU_CNT = N_ * (N_ - 1) / 2; // 165600
constexpr int NB_ = 16;                     // blocks per batch in tridiag
constexpr int NBAR_ = 640;                  // barrier slots per batch (1 per step)

// ---------------- workspace layout (bytes) ----------------
constexpr size_t OF_MSIG = 0;                                    // f32 B*N*D (aliased by invit solver scratch later)
constexpr size_t OF_SIM  = OF_MSIG + (size_t)B_*N_*D_*4;
constexpr size_t OF_A    = OF_SIM  + (size_t)B_*N_*N_*4;         // f64 Gram (also holds Householder vectors in rows)
constexpr size_t OF_MS   = OF_A    + (size_t)B_*N_*N_*8;         // f64 sigmoid row sums
constexpr size_t OF_INVN = OF_MS   + (size_t)B_*N_*8;            // f64 1/norm of raw hs rows
constexpr size_t OF_CLS  = OF_INVN + (size_t)B_*N_*8;            // f32 cls attention sums
constexpr size_t OF_DT   = OF_CLS  + (size_t)B_*N_*4;            // f64 tridiag diagonal
constexpr size_t OF_ET   = OF_DT   + (size_t)B_*N_*8;            // f64 tridiag off-diagonal
constexpr size_t OF_TAU  = OF_ET   + (size_t)B_*N_*8;            // f64 Householder taus
constexpr size_t OF_EVAL = OF_TAU  + (size_t)B_*N_*8;            // f64 top-48 eigenvalues (descending)
constexpr size_t OF_Z    = OF_EVAL + (size_t)B_*G_*8;            // f64 eigenvectors [b][q][i]
constexpr size_t OF_PART = OF_Z    + (size_t)B_*G_*N_*8;         // f64 simmean partials B*36
constexpr size_t OF_THR  = OF_PART + (size_t)B_*36*8;            // f32 thresholds (padded)
constexpr size_t OF_BEL  = OF_THR  + 64;                         // int belong
constexpr size_t OF_BAR  = OF_BEL  + (size_t)B_*N_*4;            // int barrier counters
constexpr size_t OF_FLG  = OF_BAR  + (size_t)B_*NBAR_*4;         // int flags (stride 16 per batch)
constexpr size_t OF_VB   = OF_FLG  + (size_t)B_*16*4;            // f64 vbuf (pivot-row publish)
constexpr size_t OF_WB   = OF_VB   + (size_t)B_*N_*8;            // f64 wbuf ×2 (parity double-buffer)
constexpr size_t OF_SG   = OF_WB   + (size_t)B_*2*N_*8;          // f64 sigma publish (stride 8 per batch)
constexpr size_t OF_KP   = OF_SG   + (size_t)B_*8*8;             // f64 K partials ×2 parity
constexpr size_t WS_NEEDED = OF_KP + (size_t)B_*2*NB_*8;

__device__ __forceinline__ double blockReduceD(double x, double* red) {
  int lane = threadIdx.x & 63, wv = threadIdx.x >> 6;
  int nw = (blockDim.x + 63) >> 6;
  for (int o = 32; o > 0; o >>= 1) x += __shfl_down(x, o);
  __syncthreads();                // protect red from previous use
  if (lane == 0) red[wv] = x;
  __syncthreads();
  double t = red[0];
  for (int i = 1; i < nw; i++) t += red[i];
  return t;                       // same deterministic value on all threads/blocks
}

// coherent (agent-scope, cache-bypassing) load/store for cross-block data
__device__ __forceinline__ double cload(const double* p) {
  return __hip_atomic_load(p, __ATOMIC_RELAXED, __HIP_MEMORY_SCOPE_AGENT);
}
__device__ __forceinline__ void cstore(double* p, double x) {
  __hip_atomic_store(p, x, __ATOMIC_RELAXED, __HIP_MEMORY_SCOPE_AGENT);
}

// device barrier among the NB_ blocks of one batch.
// NO __threadfence: cross-block data moves via cstore/cload (coherence-point),
// and __syncthreads drains each wave's outstanding stores (vmcnt) before entry.
// A threadfence here would emit an L2 writeback flush each step -> 2 GB of HBM
// writes per dispatch (measured R2) and ~2x step latency.
__device__ __forceinline__ void gbar(int* bar, int slot, int tid) {
  __syncthreads();
  if (tid == 0) {
    __hip_atomic_fetch_add(&bar[slot], 1, __ATOMIC_RELAXED, __HIP_MEMORY_SCOPE_AGENT);
    while (__hip_atomic_load(&bar[slot], __ATOMIC_ACQUIRE, __HIP_MEMORY_SCOPE_AGENT) < NB_)
      __builtin_amdgcn_s_sleep(2);
  }
  __syncthreads();
  __asm__ volatile("" ::: "memory");
}

// -------- K1: sigmoid features, row sums, inverse norms (+ zero barrier/flag slots) --------
__global__ void k_prep(const float* __restrict__ hs, float* __restrict__ msig,
                       double* __restrict__ ms, double* __restrict__ invn,
                       int* __restrict__ bars, int* __restrict__ flags) {
  __shared__ double red[16];
  if (blockIdx.x == 0) {
    for (int i = threadIdx.x; i < B_ * NBAR_; i += blockDim.x) bars[i] = 0;
    for (int i = threadIdx.x; i < B_ * 16; i += blockDim.x) flags[i] = 0;
  }
  int bn = blockIdx.x; int b = bn / N_, n = bn % N_;
  const float* row = hs + ((size_t)b*T_ + (n+1)) * (size_t)D_;
  float* mrow = msig + (size_t)bn * D_;
  double ssig = 0.0, ssq = 0.0;
  for (int d = threadIdx.x; d < D_; d += blockDim.x) {
    float x = row[d];
    float sg = 1.0f / (1.0f + expf(-x));
    mrow[d] = sg;
    ssig += (double)sg;
    ssq  += (double)x * (double)x;
  }
  double tot_sig = blockReduceD(ssig, red);
  double tot_sq  = blockReduceD(ssq, red);
  if (threadIdx.x == 0) {
    ms[bn] = tot_sig;
    invn[bn] = 1.0 / fmax(sqrt(tot_sq), 1e-12);
  }
}

// -------- K2: cls attention sums --------
__global__ void k_cls(const float* __restrict__ attn, float* __restrict__ cls) {
  int idx = blockIdx.x * blockDim.x + threadIdx.x;
  if (idx >= B_ * N_) return;
  int b = idx / N_, n = idx % N_;
  float s = 0.0f;
  for (int h = 0; h < H_; h++)
    s += attn[(((size_t)b*H_ + h) * T_ + 0) * T_ + (1 + n)];
  cls[idx] = s;
}

// -------- K3: tiled X*X^T GEMM; mode0 -> Gram (f64), mode1 -> cosine sim (f32) --------
__global__ void k_gemm(const float* __restrict__ hs, const float* __restrict__ msig,
                       const double* __restrict__ ms, const double* __restrict__ invn,
                       double* __restrict__ Aout, float* __restrict__ sim, int mode) {
  __shared__ float As[32][17], Bs[32][17];
  int b = blockIdx.z;
  int bi0 = blockIdx.y * 32, bj0 = blockIdx.x * 32;
  const float* base = (mode == 0) ? (msig + (size_t)b*N_*D_)
                                  : (hs + ((size_t)b*T_ + 1) * (size_t)D_);
  int tid = threadIdx.x;
  int tx = tid & 15, ty = tid >> 4;
  double a00 = 0, a01 = 0, a10 = 0, a11 = 0;
  for (int k0 = 0; k0 < D_; k0 += 16) {
    int r = tid >> 4, c = tid & 15;
    As[r][c] = base[(size_t)(bi0 + r) * D_ + k0 + c];
    Bs[r][c] = base[(size_t)(bj0 + r) * D_ + k0 + c];
    int e = tid + 256; r = e >> 4; c = e & 15;
    As[r][c] = base[(size_t)(bi0 + r) * D_ + k0 + c];
    Bs[r][c] = base[(size_t)(bj0 + r) * D_ + k0 + c];
    __syncthreads();
#pragma unroll
    for (int kk = 0; kk < 16; kk++) {
      double x0 = As[2*ty][kk],   x1 = As[2*ty+1][kk];
      double y0 = Bs[2*tx][kk],   y1 = Bs[2*tx+1][kk];
      a00 += x0*y0; a01 += x0*y1; a10 += x1*y0; a11 += x1*y1;
    }
    __syncthreads();
  }
  int i0 = bi0 + 2*ty, j0 = bj0 + 2*tx;
  if (mode == 0) {
    const double* msb = ms + (size_t)b*N_;
    double* Ab = Aout + (size_t)b*N_*N_;
    const double inv1024 = 1.0 / 1024.0;
    Ab[(size_t)i0*N_ + j0]         = a00 - msb[i0]*msb[j0]*inv1024;
    Ab[(size_t)i0*N_ + j0+1]       = a01 - msb[i0]*msb[j0+1]*inv1024;
    Ab[(size_t)(i0+1)*N_ + j0]     = a10 - msb[i0+1]*msb[j0]*inv1024;
    Ab[(size_t)(i0+1)*N_ + j0+1]   = a11 - msb[i0+1]*msb[j0+1]*inv1024;
  } else {
    const double* iv = invn + (size_t)b*N_;
    float* sb = sim + (size_t)b*N_*N_;
    sb[(size_t)i0*N_ + j0]       = (float)(a00 * iv[i0]*iv[j0]);
    sb[(size_t)i0*N_ + j0+1]     = (float)(a01 * iv[i0]*iv[j0+1]);
    sb[(size_t)(i0+1)*N_ + j0]   = (float)(a10 * iv[i0+1]*iv[j0]);
    sb[(size_t)(i0+1)*N_ + j0+1] = (float)(a11 * iv[i0+1]*iv[j0+1]);
  }
}

// -------- K4: upper-triangle sum partials --------
__global__ void k_simsum(const float* __restrict__ sim, double* __restrict__ part) {
  __shared__ double red[4];
  int blk = blockIdx.x; int b = blk / 36, s = blk % 36;
  const float* sb = sim + (size_t)b*N_*N_;
  double p = 0.0;
  for (int i = s*16; i < s*16 + 16; i++) {
    const float* row = sb + (size_t)i*N_;
    for (int j = i + 1 + threadIdx.x; j < N_; j += blockDim.x) p += (double)row[j];
  }
  double t = blockReduceD(p, red);
  if (threadIdx.x == 0) part[blk] = t;
}

__global__ void k_thr(const double* __restrict__ part, float* __restrict__ thrF) {
  int b = threadIdx.x;
  if (b < B_) {
    double s = 0.0;
    for (int i = 0; i < 36; i++) s += part[b*36 + i];
    thrF[b] = 6.0f * (float)(s / (double)TRIU_CNT);
  }
}

// -------- K5: multi-block Householder tridiagonalization, 1 barrier + 1 flag/step --------
// 16 blocks/batch, cyclic row ownership. Owner of row k+1 updates it FIRST,
// fusing sigma computation + vb publish into the update, then releases a
// monotone flag; other blocks only wait on that flag at the next step's start.
__global__ __launch_bounds__(256) void k_tridiag_mb(double* __restrict__ Aall,
    double* __restrict__ dT, double* __restrict__ eT, double* __restrict__ tauT,
    double* __restrict__ vb_all, double* __restrict__ wb_all,
    double* __restrict__ sg_all, double* __restrict__ kp_all,
    int* __restrict__ bars, int* __restrict__ flags) {
  __shared__ double v[N_], w[N_];
  __shared__ double red[4];
  int blk = blockIdx.x;
  int b = blk % B_;          // batch: clusters each batch's blocks on 2 XCDs
  int t = blk / B_;          // 0..NB_-1
  double* A  = Aall + (size_t)b*N_*N_;
  double* dv = dT   + (size_t)b*N_;
  double* ev = eT   + (size_t)b*N_;
  double* tv = tauT + (size_t)b*N_;
  double* vb = vb_all + (size_t)b*N_;
  double* wbB = wb_all + (size_t)b*2*N_;
  double* sgp = sg_all + (size_t)b*8;
  double* kpB = kp_all + (size_t)b*2*NB_;
  int* bar = bars + b*NBAR_;
  int* flagp = flags + b*16;
  int tid = threadIdx.x, lane = tid & 63, wv = tid >> 6;
  for (int k = 0; k < N_ - 2; k++) {
    double sigma, x0;
    if (k == 0) {
      double ps = 0.0;
      for (int j = 1 + tid; j < N_; j += 256) { double x = A[j]; v[j] = x; ps += x * x; }
      sigma = blockReduceD(ps, red);
      x0 = v[1];
    } else {
      if (tid == 0) {
        while (__hip_atomic_load(flagp, __ATOMIC_ACQUIRE, __HIP_MEMORY_SCOPE_AGENT) < k)
          __builtin_amdgcn_s_sleep(2);
      }
      __syncthreads();
      __asm__ volatile("" ::: "memory");
      for (int j = k + 1 + tid; j < N_; j += 256) v[j] = cload(&vb[j]);
      if (tid == 0) red[0] = cload(&sgp[0]);
      __syncthreads();
      sigma = red[0];
      x0 = v[k + 1];
    }
    double alpha, tauk;
    if (sigma == 0.0) { alpha = 0.0; tauk = 0.0; }
    else {
      alpha = (x0 >= 0.0) ? -sqrt(sigma) : sqrt(sigma);
      tauk = 1.0 / (sigma - alpha * x0);
    }
    __syncthreads();
    if (tid == 0) v[k + 1] = x0 - alpha;
    __syncthreads();
    if ((k % NB_) == t) {              // owner of row k archives reflector + d/e/tau
      if (tid == 0) { dv[k] = A[(size_t)k*N_ + k]; ev[k] = alpha; tv[k] = tauk; }
      for (int j = k + 1 + tid; j < N_; j += 256) A[(size_t)k*N_ + j] = v[j];
    }
    int rem = (t - ((k + 1) % NB_)) % NB_; if (rem < 0) rem += NB_;
    int r0 = k + 1 + rem;              // first owned row > k
    int own_next = (((k + 1) % NB_) == t);
    double* wbk = wbB + (size_t)(k & 1) * N_;
    double* kpk = kpB + (size_t)(k & 1) * NB_;
    if (tauk != 0.0) {
      // ---- matvec: w[r] = tau * A[r,:].v for owned rows; K partial fused ----
      double myk = 0.0;
      for (int r = r0 + wv*NB_; r < N_; r += 4*NB_) {
        const double* Ar = A + (size_t)r*N_;
        double pd = 0.0;
        for (int j = k + 1 + lane; j < N_; j += 64) pd += Ar[j] * v[j];
        for (int o = 32; o > 0; o >>= 1) pd += __shfl_down(pd, o);
        if (lane == 0) { double wr = tauk * pd; cstore(&wbk[r], wr); myk += v[r] * wr; }
      }
      __syncthreads();
      if (lane == 0) red[wv] = myk;
      __syncthreads();
      if (tid == 0) { double s = red[0] + red[1] + red[2] + red[3]; cstore(&kpk[t], s); }
      gbar(bar, k, tid);
      // ---- assemble w, K (fixed-order partial sum: identical in every block) ----
      for (int i = k + 1 + tid; i < N_; i += 256) w[i] = cload(&wbk[i]);
      if (tid == 0) { double s = 0.0; for (int x = 0; x < NB_; x++) s += cload(&kpk[x]); red[0] = s; }
      __syncthreads();
      double K = 0.5 * tauk * red[0];
      for (int i = k + 1 + tid; i < N_; i += 256) w[i] -= K * v[i];
      __syncthreads();
      // ---- owner updates row k+1 first: fused sigma + vb publish + flag ----
      if (own_next) {
        double vk1 = v[k+1], wk1 = w[k+1];
        double* Ar = A + (size_t)(k+1)*N_;
        double sq = 0.0;
        for (int j = k + 1 + tid; j < N_; j += 256) {
          double nv = Ar[j] - vk1 * w[j] - wk1 * v[j];
          Ar[j] = nv;
          if (j >= k + 2) { cstore(&vb[j], nv); sq += nv * nv; }
        }
        double sg2 = blockReduceD(sq, red);
        if (tid == 0) cstore(&sgp[0], sg2);
        __syncthreads();
        if (tid == 0) __hip_atomic_store(flagp, k + 1, __ATOMIC_RELAXED, __HIP_MEMORY_SCOPE_AGENT);
      }
      // ---- rank-2 update of remaining owned rows ----
      for (int r = r0 + wv*NB_; r < N_; r += 4*NB_) {
        if (own_next && r == k + 1) continue;
        double vr = v[r], wr = w[r];
        double* Ar = A + (size_t)r*N_;
        for (int j = k + 1 + lane; j < N_; j += 64) Ar[j] -= vr * w[j] + wr * v[j];
      }
    } else {
      gbar(bar, k, tid);               // keep slot alignment
      if (own_next) {
        const double* Ar = A + (size_t)(k+1)*N_;
        double sq = 0.0;
        for (int j = k + 2 + tid; j < N_; j += 256) { double nv = Ar[j]; cstore(&vb[j], nv); sq += nv * nv; }
        double sg2 = blockReduceD(sq, red);
        if (tid == 0) cstore(&sgp[0], sg2);
        __syncthreads();
        if (tid == 0) __hip_atomic_store(flagp, k + 1, __ATOMIC_RELAXED, __HIP_MEMORY_SCOPE_AGENT);
      }
    }
  }
  if (t == ((N_-2) % NB_) && tid == 0) {
    dv[N_-2] = A[(size_t)(N_-2)*N_ + (N_-2)];
    ev[N_-2] = A[(size_t)(N_-2)*N_ + (N_-1)];
  }
  if (t == ((N_-1) % NB_) && tid == 0) dv[N_-1] = A[(size_t)(N_-1)*N_ + (N_-1)];
  if (t == 0 && tid == 0) { ev[N_-1] = 0.0; tv[N_-2] = 0.0; tv[N_-1] = 0.0; }
}

// -------- K6: top-48 eigenvalues, 64-point multisection, one wave per (b, j) --------
__global__ __launch_bounds__(64) void k_eigvals_ms(const double* __restrict__ dT,
    const double* __restrict__ eT, double* __restrict__ eval) {
  __shared__ double sd[N_], se[N_];
  int blk = blockIdx.x; int b = blk / G_, j = blk % G_;
  for (int i = threadIdx.x; i < N_; i += 64) {
    sd[i] = dT[(size_t)b*N_ + i];
    se[i] = eT[(size_t)b*N_ + i];
  }
  __syncthreads();
  int lane = threadIdx.x;
  double lo = 1e300, hi = -1e300;
  for (int i = lane; i < N_; i += 64) {
    double r = ((i > 0) ? fabs(se[i-1]) : 0.0) + ((i < N_-1) ? fabs(se[i]) : 0.0);
    lo = fmin(lo, sd[i] - r); hi = fmax(hi, sd[i] + r);
  }
  for (int o = 32; o > 0; o >>= 1) {
    lo = fmin(lo, __shfl_xor(lo, o));
    hi = fmax(hi, __shfl_xor(hi, o));
  }
  double span = hi - lo + 1e-30;
  lo -= span * 1e-6; hi += span * 1e-6;
  int target = N_ - 1 - j;  // ascending index of j-th largest
  const double PIV = 1e-280;
  for (int round = 0; round < 11; round++) {
    double width = hi - lo;
    double mid = lo + width * ((double)(lane + 1) / 65.0);
    int cnt = 0;
    double q = sd[0] - mid;
    if (q <= PIV) { cnt++; q = fmin(q, -PIV); }
    for (int i = 1; i < N_; i++) {
      q = (sd[i] - mid) - se[i-1]*se[i-1] / q;
      if (q <= PIV) { cnt++; q = fmin(q, -PIV); }
    }
    unsigned long long mask = __ballot(cnt > target);
    double nlo, nhi;
    if (mask == 0ULL) { nlo = lo + width * (64.0 / 65.0); nhi = hi; }
    else {
      int m = __ffsll(mask) - 1;
      nhi = lo + width * ((double)(m + 1) / 65.0);
      nlo = (m == 0) ? lo : lo + width * ((double)m / 65.0);
    }
    lo = nlo; hi = nhi;
  }
  if (lane == 0) eval[(size_t)b*G_ + j] = 0.5 * (lo + hi);
}

// -------- K7: inverse iteration (lane per eigenvector) + rare cluster re-orth --------
__global__ void k_eigvecs(const double* __restrict__ dT, const double* __restrict__ eT,
    const double* __restrict__ eval,
    double* __restrict__ Ud, double* __restrict__ U1, double* __restrict__ U2,
    double* __restrict__ Um, int* __restrict__ Ufl, double* __restrict__ Yv,
    double* __restrict__ Z) {
  __shared__ double sd[N_], se[N_];
  __shared__ double red0;
  __shared__ int cstart[G_];
  __shared__ double sh_ev[G_];
  int b = blockIdx.x;
  for (int i = threadIdx.x; i < N_; i += blockDim.x) {
    sd[i] = dT[(size_t)b*N_ + i]; se[i] = eT[(size_t)b*N_ + i];
  }
  if (threadIdx.x < G_) sh_ev[threadIdx.x] = eval[(size_t)b*G_ + threadIdx.x];
  __syncthreads();
  int j = threadIdx.x;
  size_t sbase = (size_t)b * N_ * G_;
  double* ud = Ud + sbase; double* u1 = U1 + sbase; double* u2 = U2 + sbase;
  double* um = Um + sbase; int* ufl = Ufl + sbase; double* yv = Yv + sbase;
  if (j < G_) {
    double lam = sh_ev[j];
    double GU = 1e-30 * (1.0 + fabs(lam));
    double ak = sd[0] - lam;
    double bk = se[0];
    for (int k = 0; k < N_ - 1; k++) {
      double sub = se[k];
      double diag1 = sd[k+1] - lam;
      double sup1 = (k < N_ - 2) ? se[k+1] : 0.0;
      double udv, u1v, u2v, umv; int flv;
      if (fabs(ak) >= fabs(sub)) {
        double piv = ak;
        if (fabs(piv) < GU) piv = (piv >= 0.0) ? GU : -GU;
        double ml = sub / piv;
        udv = piv; u1v = bk; u2v = 0.0; umv = ml; flv = 0;
        ak = diag1 - ml * bk; bk = sup1;
      } else {
        double ml = ak / sub;
        udv = sub; u1v = diag1; u2v = sup1; umv = ml; flv = 1;
        ak = bk - ml * diag1; bk = -ml * sup1;
      }
      ud[(size_t)k*G_+j] = udv; u1[(size_t)k*G_+j] = u1v; u2[(size_t)k*G_+j] = u2v;
      um[(size_t)k*G_+j] = umv; ufl[(size_t)k*G_+j] = flv;
    }
    { double piv = ak; if (fabs(piv) < GU) piv = (piv >= 0.0) ? GU : -GU;
      ud[(size_t)(N_-1)*G_+j] = piv; u1[(size_t)(N_-1)*G_+j] = 0.0; u2[(size_t)(N_-1)*G_+j] = 0.0; }
    for (int i = 0; i < N_; i++) {
      unsigned s = (unsigned)(i * 2654435761u) ^ (unsigned)((j + 1) * 40503u) ^ (unsigned)(b * 2246822519u);
      s = s * 1664525u + 1013904223u;
      s ^= s >> 16; s = s * 2246822519u;
      double rv = ((double)(s >> 8) * (1.0 / 16777216.0)) * 2.0 - 1.0;
      if (fabs(rv) < 1e-3) rv = 0.5;
      yv[(size_t)i*G_+j] = rv;
    }
    for (int it = 0; it < 3; it++) {
      if (it) {
        double mx = 0.0;
        for (int i = 0; i < N_; i++) mx = fmax(mx, fabs(yv[(size_t)i*G_+j]));
        double sc = 1.0 / fmax(mx, 1e-300);
        for (int i = 0; i < N_; i++) yv[(size_t)i*G_+j] *= sc;
      }
      for (int k = 0; k < N_ - 1; k++) {
        double yk = yv[(size_t)k*G_+j], yk1 = yv[(size_t)(k+1)*G_+j];
        if (ufl[(size_t)k*G_+j]) { double tt = yk; yk = yk1; yk1 = tt; }
        yk1 -= um[(size_t)k*G_+j] * yk;
        yv[(size_t)k*G_+j] = yk; yv[(size_t)(k+1)*G_+j] = yk1;
      }
      double y1, y2 = 0.0;
      { double tt = yv[(size_t)(N_-1)*G_+j] / ud[(size_t)(N_-1)*G_+j];
        yv[(size_t)(N_-1)*G_+j] = tt; y1 = tt; }
      for (int k = N_ - 2; k >= 0; k--) {
        double tt = yv[(size_t)k*G_+j] - u1[(size_t)k*G_+j]*y1 - u2[(size_t)k*G_+j]*y2;
        tt /= ud[(size_t)k*G_+j];
        yv[(size_t)k*G_+j] = tt;
        y2 = y1; y1 = tt;
      }
    }
    double s2 = 0.0;
    for (int i = 0; i < N_; i++) { double tt = yv[(size_t)i*G_+j]; s2 += tt * tt; }
    double inv = 1.0 / sqrt(fmax(s2, 1e-300));
    double* Zj = Z + ((size_t)b*G_ + j) * N_;
    for (int i = 0; i < N_; i++) Zj[i] = yv[(size_t)i*G_+j] * inv;
  }
  __syncthreads();
  if (threadIdx.x == 0) {
    double tol = 1e-10 * (fabs(sh_ev[0]) + 1.0);
    cstart[0] = 0;
    for (int q = 1; q < G_; q++)
      cstart[q] = ((sh_ev[q-1] - sh_ev[q]) < tol) ? cstart[q-1] : q;
  }
  __syncthreads();
  for (int q = 1; q < G_; q++) {
    if (cstart[q] == q) continue;
    double* Zq = Z + ((size_t)b*G_ + q) * N_;
    for (int p = cstart[q]; p < q; p++) {
      double* Zp = Z + ((size_t)b*G_ + p) * N_;
      double dp = 0.0;
      for (int i = threadIdx.x; i < N_; i += blockDim.x) dp += Zq[i] * Zp[i];
      for (int o = 32; o > 0; o >>= 1) dp += __shfl_down(dp, o);
      if (threadIdx.x == 0) red0 = dp;
      __syncthreads();
      double dd = red0;
      for (int i = threadIdx.x; i < N_; i += blockDim.x) Zq[i] -= dd * Zp[i];
      __syncthreads();
    }
    double s2 = 0.0;
    for (int i = threadIdx.x; i < N_; i += blockDim.x) { double tt = Zq[i]; s2 += tt * tt; }
    for (int o = 32; o > 0; o >>= 1) s2 += __shfl_down(s2, o);
    if (threadIdx.x == 0) red0 = s2;
    __syncthreads();
    double inv = 1.0 / sqrt(fmax(red0, 1e-300));
    for (int i = threadIdx.x; i < N_; i += blockDim.x) Zq[i] *= inv;
    __syncthreads();
  }
}

// -------- K8: back-transform, one wave per (batch, eigenvector), Z in registers --------
__global__ __launch_bounds__(64) void k_backxf_mb(const double* __restrict__ Aall,
    const double* __restrict__ tauT, double* __restrict__ Z) {
  int blk = blockIdx.x;
  int b = blk / G_, q = blk % G_;
  const double* A = Aall + (size_t)b*N_*N_;
  const double* tau = tauT + (size_t)b*N_;
  double* Zq = Z + ((size_t)b*G_ + q) * N_;
  int lane = threadIdx.x;
  double z[9];
#pragma unroll
  for (int m = 0; m < 9; m++) z[m] = Zq[lane + 64*m];
  for (int k = N_ - 3; k >= 0; k--) {
    double t = tau[k];
    if (t == 0.0) continue;
    const double* vk = A + (size_t)k*N_;
    double vv[9]; double p = 0.0;
#pragma unroll
    for (int m = 0; m < 9; m++) {
      int i = lane + 64*m;
      double vi = (i > k) ? vk[i] : 0.0;
      vv[m] = vi; p += vi * z[m];
    }
    for (int o = 32; o > 0; o >>= 1) p += __shfl_down(p, o);
    p = __shfl(p, 0);
    double s = t * p;
#pragma unroll
    for (int m = 0; m < 9; m++) z[m] -= s * vv[m];
  }
#pragma unroll
  for (int m = 0; m < 9; m++) Zq[lane + 64*m] = z[m];
}

// -------- K9: belong = argmax_q |V[n][q]| (first max) --------
__global__ void k_belong(const double* __restrict__ Z, int* __restrict__ belong) {
  int idx = blockIdx.x * blockDim.x + threadIdx.x;
  if (idx >= B_ * N_) return;
  int b = idx / N_, n = idx % N_;
  const double* Zb = Z + (size_t)b*G_*N_;
  double best = -1.0; int bi = 0;
  for (int q = 0; q < G_; q++) {
    double av = fabs(Zb[(size_t)q*N_ + n]);
    if (av > best) { best = av; bi = q; }
  }
  belong[idx] = bi;
}

// -------- K10: NMS + quota scheduling + index emission (one block per batch) --------
__global__ __launch_bounds__(256) void k_nms(const float* __restrict__ sim,
    const float* __restrict__ cls, const int* __restrict__ belong,
    const float* __restrict__ thrF, float* __restrict__ outF) {
  __shared__ float nsv[N_], rsv[N_];
  __shared__ int bl_s[N_];
  __shared__ int lists[N_];
  __shared__ int off[G_ + 1];
  __shared__ int kc[G_], gc[G_], lowv[G_], upv[G_], tokd[G_], sortg[G_], pre[G_ + 1];
  __shared__ int gathered[L_];
  __shared__ int anyv;
  __shared__ float shthr;
  int b = blockIdx.x, tid = threadIdx.x;
  const float* simb = sim + (size_t)b*N_*N_;
  if (tid == 0) shthr = thrF[b];
  if (tid < G_) gc[tid] = 0;
  __syncthreads();
  for (int i = tid; i < N_; i += 256) {
    int g = belong[b*N_ + i];
    bl_s[i] = g;
    float sc = cls[b*N_ + i];
    nsv[i] = sc; rsv[i] = sc;
    atomicAdd(&gc[g], 1);
  }
  __syncthreads();
  if (tid == 0) {           // deterministic (ascending-n) group list build
    off[0] = 0;
    for (int g = 0; g < G_; g++) off[g+1] = off[g] + gc[g];
    for (int g = 0; g < G_; g++) pre[g] = off[g];
    for (int n = 0; n < N_; n++) lists[pre[bl_s[n]]++] = n;
  }
  __syncthreads();
  float thr = shthr;
  float gs = 1000.0f;
  int myc = 0;
  for (int iter = 0; iter < N_ + 8; iter++) {
    if (tid == 0) anyv = 0;
    __syncthreads();
    int m = -1;
    if (tid < G_) {
      float mx = 0.0f;
      for (int a = off[tid]; a < off[tid+1]; a++) {
        int n2 = lists[a];
        float vv = nsv[n2];
        if (vv > mx) { mx = vv; m = n2; }
      }
      if (m >= 0) anyv = 1;
    }
    __syncthreads();
    if (m >= 0) {
      rsv[m] = gs;
      nsv[m] = 0.0f;
      const float* srow = simb + (size_t)m*N_;
      for (int a = off[tid]; a < off[tid+1]; a++) {
        int n2 = lists[a];
        if (nsv[n2] > 0.0f && srow[n2] > thr) nsv[n2] = 0.0f;
      }
      myc++;
    }
    gs -= 1.0f;
    __syncthreads();
    if (!anyv) break;
  }
  if (tid < G_) kc[tid] = myc;
  __syncthreads();
  if (tid == 0) {
    int sumkc = 0; for (int g = 0; g < G_; g++) sumkc += kc[g];
    int sumlow = 0;
    for (int g = 0; g < G_; g++) {
      lowv[g] = (gc[g] < 1) ? gc[g] : 1;
      int u = 15; if (gc[g] < u) u = gc[g]; if (kc[g] < u) u = kc[g];
      upv[g] = u; sumlow += lowv[g];
    }
    int su = 0; for (int g = 0; g < G_; g++) su += upv[g];
    while (su < NEED_) {
      su = 0;
      for (int g = 0; g < G_; g++) { int u = upv[g] + 1; if (u > gc[g]) u = gc[g]; upv[g] = u; su += u; }
    }
    int other = NEED_ - sumlow - 1; if (other < 0) other = 0;
    float s = (float)sumkc;
    float c = 0.0f; int prevR = 0;
    float otherf = (float)other;
    for (int g = 0; g < G_; g++) {
      float nc = (float)kc[g] / s;
      c += nc;
      int R = (int)rintf(c * otherf);          // round half-to-even like jnp.round
      int od = R - prevR; prevR = R;
      int t0 = od + lowv[g]; if (t0 > upv[g]) t0 = upv[g];
      tokd[g] = t0;
    }
    for (int g = 0; g < G_; g++) sortg[g] = g;
    for (int a = 1; a < G_; a++) {            // stable insertion sort, kc descending
      int vIdx = sortg[a]; int key = kc[vIdx]; int p2 = a - 1;
      while (p2 >= 0 && kc[sortg[p2]] < key) { sortg[p2+1] = sortg[p2]; p2--; }
      sortg[p2+1] = vIdx;
    }
    int target = other + sumlow;
    int sumd = 0; for (int g = 0; g < G_; g++) sumd += tokd[g];
    int fg = 0;
    while (sumd < target) {
      int gi = sortg[(fg < G_-1) ? fg : (G_-1)];
      int fill = upv[gi] - tokd[gi];
      int rem = target - sumd;
      if (rem < fill) fill = rem;
      tokd[gi] += fill; sumd += fill;
      fg++;
      if (fg > 100000) break;
    }
    pre[0] = 0; for (int g = 0; g < G_; g++) pre[g+1] = pre[g] + tokd[g];
  }
  __syncthreads();
  for (int i = tid; i < L_; i += 256) gathered[i] = 0;
  __syncthreads();
  if (tid < G_) {
    int g = tid;
    int td = tokd[g], base = pre[g];
    for (int t = 0; t < td; t++) {
      float bv = -3e38f; int bn2 = 0;
      for (int a = off[g]; a < off[g+1]; a++) {
        int n2 = lists[a];
        float vv = rsv[n2];
        if (vv > bv) { bv = vv; bn2 = n2; }
      }
      rsv[bn2] = -3e38f;
      int pos = base + t;
      if (pos < L_) gathered[pos] = bn2;
    }
  }
  __syncthreads();
  if (tid < NEED_) {
    float val = (tid == 0) ? 0.0f : (float)(gathered[tid - 1] + 1);
    outF[(size_t)B_*NEED_*D_ + (size_t)b*NEED_ + tid] = val;
  }
}

// -------- K11: gather selected hidden rows --------
__global__ void k_gather(const float* __restrict__ hs, float* __restrict__ outF) {
  int blk = blockIdx.x;
  int b = blk / NEED_, i = blk % NEED_;
  int idx = (int)outF[(size_t)B_*NEED_*D_ + (size_t)b*NEED_ + i];
  const float4* src = (const float4*)(hs + ((size_t)b*T_ + idx) * (size_t)D_);
  float4* dst = (float4*)(outF + ((size_t)b*NEED_ + i) * (size_t)D_);
  dst[threadIdx.x] = src[threadIdx.x];
}

extern "C" void kernel_launch(void* const* d_in, const int* in_sizes, int n_in,
                              void* d_out, int out_size, void* d_ws, size_t ws_size,
                              hipStream_t stream) {
  if (ws_size < WS_NEEDED) return;
  const float* hs   = (const float*)d_in[0];
  const float* attn = (const float*)d_in[1];
  float* outF = (float*)d_out;
  char* w = (char*)d_ws;
  float*  msig = (float*)(w + OF_MSIG);
  float*  sim  = (float*)(w + OF_SIM);
  double* A    = (double*)(w + OF_A);
  double* ms   = (double*)(w + OF_MS);
  double* invn = (double*)(w + OF_INVN);
  float*  cls  = (float*)(w + OF_CLS);
  double* dT   = (double*)(w + OF_DT);
  double* eT   = (double*)(w + OF_ET);
  double* tauT = (double*)(w + OF_TAU);
  double* eval = (double*)(w + OF_EVAL);
  double* Z    = (double*)(w + OF_Z);
  double* part = (double*)(w + OF_PART);
  float*  thrF = (float*)(w + OF_THR);
  int*    belong = (int*)(w + OF_BEL);
  int*    bars = (int*)(w + OF_BAR);
  int*    flags = (int*)(w + OF_FLG);
  double* vb   = (double*)(w + OF_VB);
  double* wb   = (double*)(w + OF_WB);
  double* sg   = (double*)(w + OF_SG);
  double* kp   = (double*)(w + OF_KP);
  // inverse-iteration scratch aliases msig region (msig dead after the Gram GEMM)
  double* Ud = (double*)(w + OF_MSIG);
  double* U1 = Ud + (size_t)B_*N_*G_;
  double* U2 = U1 + (size_t)B_*N_*G_;
  double* Um = U2 + (size_t)B_*N_*G_;
  double* Yv = Um + (size_t)B_*N_*G_;
  int*    Ufl = (int*)(Yv + (size_t)B_*N_*G_);

  k_prep<<<B_*N_, 256, 0, stream>>>(hs, msig, ms, invn, bars, flags);
  k_cls<<<(B_*N_ + 255)/256, 256, 0, stream>>>(attn, cls);
  k_gemm<<<dim3(N_/32, N_/32, B_), 256, 0, stream>>>(hs, msig, ms, invn, A, sim, 0);
  k_gemm<<<dim3(N_/32, N_/32, B_), 256, 0, stream>>>(hs, msig, ms, invn, A, sim, 1);
  k_simsum<<<B_*36, 256, 0, stream>>>(sim, part);
  k_thr<<<1, 64, 0, stream>>>(part, thrF);
  k_tridiag_mb<<<B_*NB_, 256, 0, stream>>>(A, dT, eT, tauT, vb, wb, sg, kp, bars, flags);
  k_eigvals_ms<<<B_*G_, 64, 0, stream>>>(dT, eT, eval);
  k_eigvecs<<<B_, 64, 0, stream>>>(dT, eT, eval, Ud, U1, U2, Um, Ufl, Yv, Z);
  k_backxf_mb<<<B_*G_, 64, 0, stream>>>(A, tauT, Z);
  k_belong<<<(B_*N_ + 255)/256, 256, 0, stream>>>(Z, belong);
  k_nms<<<B_, 256, 0, stream>>>(sim, cls, belong, thrF, outF);
  k_gather<<<B_*NEED_, 256, 0, stream>>>(hs, outF);
}